// Round 7
// baseline (467.885 us; speedup 1.0000x reference)
//
#include <hip/hip_runtime.h>
#include <cstdint>
#include <cstddef>

#define INORM_EPS 1e-5f

typedef _Float16 f16;
typedef f16 f16x8 __attribute__((ext_vector_type(8)));
typedef f16 f16x4 __attribute__((ext_vector_type(4)));
typedef float f32x4 __attribute__((ext_vector_type(4)));

// ------- merged prep (zero SP, pack weights) + input stats partials -------
__global__ __launch_bounds__(256) void prep_stats(
    const float* __restrict__ rbs_w1, const float* __restrict__ rbs_w2,
    const float* __restrict__ rb_w1, const float* __restrict__ rb_w2,
    const float* __restrict__ rbs_ws, const float* __restrict__ conv1_w,
    const float* __restrict__ x, float2* __restrict__ SP,
    f16* __restrict__ wp3, f16* __restrict__ wp1, f16* __restrict__ wp7,
    float2* __restrict__ SPx8) {
  const int bx = blockIdx.x;
  if (bx >= 480) {
    const int g = bx - 480;
    const int map = g >> 3, chunk = g & 7;
    const float4* p = (const float4*)(x + (size_t)map * 65536 + (size_t)chunk * 8192);
    float s = 0.f, ss = 0.f;
    for (int i = threadIdx.x; i < 2048; i += 256) {
      float4 v = p[i];
      s += v.x + v.y + v.z + v.w;
      ss += v.x * v.x + v.y * v.y + v.z * v.z + v.w * v.w;
    }
    __shared__ float r0[256], r1[256];
    r0[threadIdx.x] = s;
    r1[threadIdx.x] = ss;
    __syncthreads();
    for (int off = 128; off > 0; off >>= 1) {
      if ((int)threadIdx.x < off) {
        r0[threadIdx.x] += r0[threadIdx.x + off];
        r1[threadIdx.x] += r1[threadIdx.x + off];
      }
      __syncthreads();
    }
    if (threadIdx.x == 0) SPx8[map * 8 + chunk] = make_float2(r0[0], r1[0]);
    return;
  }
  int i = bx * 256 + threadIdx.x;
  if (i < 20480) { SP[i] = make_float2(0.f, 0.f); return; }
  i -= 20480;
  if (i < 92160) {  // [mat][9 taps][2 halves][64 lanes][8] ; B-frag layout
    int mat = i / 9216, r = i % 9216;
    int p = r >> 10, f = (r >> 9) & 1, l = (r >> 3) & 63, j = r & 7;
    int co = f * 16 + (l & 15), ci = (l >> 4) * 8 + j;
    const float* src; int m;
    if (mat < 3) { src = rbs_w1; m = mat; }
    else if (mat < 6) { src = rbs_w2; m = mat - 3; }
    else if (mat < 8) { src = rb_w1; m = mat - 6; }
    else { src = rb_w2; m = mat - 8; }
    wp3[i] = (f16)src[m * 9216 + co * 288 + ci * 9 + p];
    return;
  }
  i -= 92160;
  if (i < 3072) {
    int mat = i / 1024, r = i % 1024;
    int f = r >> 9, l = (r >> 3) & 63, j = r & 7;
    wp1[i] = (f16)rbs_ws[mat * 1024 + (f * 16 + (l & 15)) * 32 + (l >> 4) * 8 + j];
    return;
  }
  i -= 3072;
  if (i >= 7168) return;
  int ky = i >> 10, f = (i >> 9) & 1, l = (i >> 3) & 63, j = i & 7;
  int k = (l >> 4) * 8 + j, kx = k >> 2, ci = k & 3;
  float v = 0.f;
  if (kx < 7 && ci < 3) v = conv1_w[(f * 16 + (l & 15)) * 147 + ci * 49 + ky * 7 + kx];
  wp7[i] = (f16)v;
}

// ---------------- MFMA 3x3 stride-1 conv, rolling row window --------------
// Transposed MFMA output (mfma(W, X^T)): lane holds 4 consecutive channels
// of one pixel -> vectorized f16x4 stores + vectorized SKIP1 reads.
template <int W, int SKIP, int RPB>
__global__ __launch_bounds__(256) void conv3r(
    const f16* __restrict__ Rin, const float2* __restrict__ SPin, float inv_hw,
    const f16* __restrict__ wp, const float* __restrict__ bias,
    const float* __restrict__ bias2, const f16* __restrict__ skip,
    const f16* __restrict__ wps, f16* __restrict__ Rout,
    float2* __restrict__ ostats) {
  constexpr int TPR = W / 16;
  constexpr int LEN = (RPB * TPR) / 4;
  const int t = threadIdx.x, w = t >> 6, l = t & 63;
  const int n = l & 15, q = l >> 4;
  const int b = blockIdx.z;
  const int tx = w % TPR;
  const int y0 = blockIdx.x * RPB + (w / TPR) * LEN;
  const int x = (tx << 4) + n;
  const f16* Rb = Rin + (size_t)b * W * W * 32;

  f16x8 sc, sh;
#pragma unroll
  for (int j = 0; j < 8; j++) {
    float2 s = SPin[b * 32 + q * 8 + j];
    float mean = s.x * inv_hw;
    float rstd = rsqrtf(s.y * inv_hw - mean * mean + INORM_EPS);
    sc[j] = (f16)rstd;
    sh[j] = (f16)(-mean * rstd);
  }

  f16x8 wf[18];
#pragma unroll
  for (int i = 0; i < 18; i++) wf[i] = *(const f16x8*)(wp + i * 512 + l * 8);
  f16x8 wsf0, wsf1;
  if (SKIP == 2) {
    wsf0 = *(const f16x8*)(wps + l * 8);
    wsf1 = *(const f16x8*)(wps + 512 + l * 8);
  }
  float bb0[4], bb1[4];
#pragma unroll
  for (int r = 0; r < 4; r++) {
    bb0[r] = bias[q * 4 + r];
    bb1[r] = bias[16 + q * 4 + r];
    if (SKIP == 2) { bb0[r] += bias2[q * 4 + r]; bb1[r] += bias2[16 + q * 4 + r]; }
  }

  f16* ro = Rout + (size_t)b * W * W * 32;
  const f16* sb = skip ? skip + (size_t)b * (SKIP == 2 ? 4 : 1) * W * W * 32 : nullptr;

  bool okc[3];
#pragma unroll
  for (int kx = 0; kx < 3; kx++) okc[kx] = (unsigned)(x + kx - 1) < (unsigned)W;

  auto rowload = [&](int gy, f16x8* dst) {
    int gyc = min(max(gy, 0), W - 1);
#pragma unroll
    for (int kx = 0; kx < 3; kx++) {
      int gxc = min(max(x + kx - 1, 0), W - 1);
      dst[kx] = *(const f16x8*)(Rb + ((size_t)gyc * W + gxc) * 32 + q * 8);
    }
  };
  auto rownorm = [&](int gy, const f16x8* src, f16x8* dst) {
    bool okr = (unsigned)gy < (unsigned)W;
#pragma unroll
    for (int kx = 0; kx < 3; kx++) {
      f16x8 v = src[kx] * sc + sh;
#pragma unroll
      for (int e = 0; e < 8; e++) v[e] = v[e] > (f16)0 ? v[e] : (f16)0;
      f16x8 z = {};
      dst[kx] = (okr && okc[kx]) ? v : z;
    }
  };

  float sm0v[4] = {}, sq0v[4] = {}, sm1v[4] = {}, sq1v[4] = {};
  f16x8 win[9];
  f16x8 pf[2][3];
#pragma unroll
  for (int jj = 0; jj < 3; jj++) rowload(y0 + jj - 1, &win[jj * 3]);
  if (LEN > 1) rowload(y0 + 2, pf[0]);
#pragma unroll
  for (int jj = 0; jj < 3; jj++) rownorm(y0 + jj - 1, &win[jj * 3], &win[jj * 3]);

#pragma unroll
  for (int i = 0; i < LEN; i++) {
    int y = y0 + i;
    if (i + 2 < LEN) rowload(y0 + i + 3, pf[(i + 1) & 1]);
    f32x4 acc0 = {0.f, 0.f, 0.f, 0.f}, acc1 = {0.f, 0.f, 0.f, 0.f};
#pragma unroll
    for (int ky = 0; ky < 3; ky++) {
      int slot = (i + ky) % 3;
#pragma unroll
      for (int kx = 0; kx < 3; kx++) {
        f16x8 a = win[slot * 3 + kx];
        acc0 = __builtin_amdgcn_mfma_f32_16x16x32_f16(wf[2 * (ky * 3 + kx)], a, acc0, 0, 0, 0);
        acc1 = __builtin_amdgcn_mfma_f32_16x16x32_f16(wf[2 * (ky * 3 + kx) + 1], a, acc1, 0, 0, 0);
      }
    }
    if (SKIP == 2) {
      const int Ws = 2 * W;
      f16x8 as = *(const f16x8*)(sb + ((size_t)(2 * y) * Ws + 2 * x) * 32 + q * 8);
      acc0 = __builtin_amdgcn_mfma_f32_16x16x32_f16(wsf0, as, acc0, 0, 0, 0);
      acc1 = __builtin_amdgcn_mfma_f32_16x16x32_f16(wsf1, as, acc1, 0, 0, 0);
    }
    size_t px = (size_t)y * W + (tx << 4) + n;
    f16x4 s0, s1;
    if (SKIP == 1) {
      s0 = *(const f16x4*)(sb + px * 32 + q * 4);
      s1 = *(const f16x4*)(sb + px * 32 + 16 + q * 4);
    }
    f16x4 o0, o1;
#pragma unroll
    for (int r = 0; r < 4; r++) {
      float v0 = acc0[r] + bb0[r];
      float v1 = acc1[r] + bb1[r];
      if (SKIP == 1) { v0 += (float)s0[r]; v1 += (float)s1[r]; }
      o0[r] = (f16)v0; o1[r] = (f16)v1;
      sm0v[r] += v0; sq0v[r] += v0 * v0;
      sm1v[r] += v1; sq1v[r] += v1 * v1;
    }
    *(f16x4*)(ro + px * 32 + q * 4) = o0;
    *(f16x4*)(ro + px * 32 + 16 + q * 4) = o1;
    if (i + 1 < LEN) rownorm(y0 + i + 2, pf[i & 1], &win[(i % 3) * 3]);
  }
  if (ostats) {
#pragma unroll
    for (int r = 0; r < 4; r++) {
#pragma unroll
      for (int d = 1; d < 16; d <<= 1) {
        sm0v[r] += __shfl_xor(sm0v[r], d);
        sq0v[r] += __shfl_xor(sq0v[r], d);
        sm1v[r] += __shfl_xor(sm1v[r], d);
        sq1v[r] += __shfl_xor(sq1v[r], d);
      }
    }
    if (n == 0) {
#pragma unroll
      for (int r = 0; r < 4; r++) {
        atomicAdd(&ostats[b * 32 + q * 4 + r].x, sm0v[r]);
        atomicAdd(&ostats[b * 32 + q * 4 + r].y, sq0v[r]);
        atomicAdd(&ostats[b * 32 + 16 + q * 4 + r].x, sm1v[r]);
        atomicAdd(&ostats[b * 32 + 16 + q * 4 + r].y, sq1v[r]);
      }
    }
  }
}

// ---------------- MFMA 3x3 conv (pipelined units): stride-2 and 16x16 -----
// Transposed MFMA output, vectorized stores (see conv3r).
template <int WIN, int STRIDE, int SKIP, int RPB>
__global__ __launch_bounds__(256) void conv3n(
    const f16* __restrict__ Rin, const float2* __restrict__ SPin, float inv_hw,
    const f16* __restrict__ wp, const float* __restrict__ bias,
    const float* __restrict__ bias2, const f16* __restrict__ skip,
    const f16* __restrict__ wps, f16* __restrict__ Rout,
    float2* __restrict__ ostats) {
  constexpr int WOUT = WIN / STRIDE;
  constexpr int TPR = WOUT / 16;
  constexpr int UNITS = TPR * RPB;
  constexpr int U = UNITS / 4;
  static_assert(U >= 1, "need at least one unit per wave");
  constexpr int NB = (U >= 3) ? 3 : ((U >= 2) ? 2 : 1);
  const int t = threadIdx.x, w = t >> 6, l = t & 63;
  const int n = l & 15, q = l >> 4;
  const int b = blockIdx.z;
  const int yb = blockIdx.x * RPB;
  const f16* Rb = Rin + (size_t)b * WIN * WIN * 32;

  f16x8 sc, sh;
#pragma unroll
  for (int j = 0; j < 8; j++) {
    float2 s = SPin[b * 32 + q * 8 + j];
    float mean = s.x * inv_hw;
    float rstd = rsqrtf(s.y * inv_hw - mean * mean + INORM_EPS);
    sc[j] = (f16)rstd;
    sh[j] = (f16)(-mean * rstd);
  }

  f16x8 wf[18];
#pragma unroll
  for (int i = 0; i < 18; i++) wf[i] = *(const f16x8*)(wp + i * 512 + l * 8);
  f16x8 wsf0, wsf1;
  if (SKIP == 2) {
    wsf0 = *(const f16x8*)(wps + l * 8);
    wsf1 = *(const f16x8*)(wps + 512 + l * 8);
  }
  float bb0[4], bb1[4];
#pragma unroll
  for (int r = 0; r < 4; r++) {
    bb0[r] = bias[q * 4 + r];
    bb1[r] = bias[16 + q * 4 + r];
    if (SKIP == 2) { bb0[r] += bias2[q * 4 + r]; bb1[r] += bias2[16 + q * 4 + r]; }
  }

  f16* ro = Rout + (size_t)b * WOUT * WOUT * 32;
  const f16* sb = skip ? skip + (size_t)b * (SKIP == 2 ? 4 : 1) * WOUT * WOUT * 32 : nullptr;

  auto load_u = [&](int u, f16x8* a) {
    int ty = u / TPR, tx = u % TPR;
    int y = yb + ty;
#pragma unroll
    for (int kx = 0; kx < 3; kx++) {
      int gx = STRIDE * ((tx << 4) + n) + kx - 1;
      int gxc = min(max(gx, 0), WIN - 1);
#pragma unroll
      for (int ky = 0; ky < 3; ky++) {
        int gy = STRIDE * y + ky - 1;
        int gyc = min(max(gy, 0), WIN - 1);
        a[ky * 3 + kx] = *(const f16x8*)(Rb + ((size_t)gyc * WIN + gxc) * 32 + q * 8);
      }
    }
  };
  auto norm_u = [&](int u, f16x8* a) {
    int ty = u / TPR, tx = u % TPR;
    int y = yb + ty;
#pragma unroll
    for (int kx = 0; kx < 3; kx++) {
      int gx = STRIDE * ((tx << 4) + n) + kx - 1;
      bool okx = (unsigned)gx < (unsigned)WIN;
#pragma unroll
      for (int ky = 0; ky < 3; ky++) {
        int gy = STRIDE * y + ky - 1;
        bool ok = okx && ((unsigned)gy < (unsigned)WIN);
        f16x8 v = a[ky * 3 + kx] * sc + sh;
#pragma unroll
        for (int e = 0; e < 8; e++) v[e] = v[e] > (f16)0 ? v[e] : (f16)0;
        f16x8 z = {};
        a[ky * 3 + kx] = ok ? v : z;
      }
    }
  };

  float sm0v[4] = {}, sq0v[4] = {}, sm1v[4] = {}, sq1v[4] = {};
  f16x8 buf[NB][9];
  load_u(w, buf[0]);
  if (U > 1) load_u(w + 4, buf[1 % NB]);
#pragma unroll
  for (int i = 0; i < U; i++) {
    int u = w + 4 * i;
    if (i + 2 < U) load_u(u + 8, buf[(i + 2) % NB]);
    f16x8* a = buf[i % NB];
    norm_u(u, a);
    int ty = u / TPR, tx = u % TPR;
    int y = yb + ty, x0 = tx << 4;
    f32x4 acc0 = {0.f, 0.f, 0.f, 0.f}, acc1 = {0.f, 0.f, 0.f, 0.f};
#pragma unroll
    for (int p = 0; p < 9; p++) {
      acc0 = __builtin_amdgcn_mfma_f32_16x16x32_f16(wf[2 * p], a[p], acc0, 0, 0, 0);
      acc1 = __builtin_amdgcn_mfma_f32_16x16x32_f16(wf[2 * p + 1], a[p], acc1, 0, 0, 0);
    }
    if (SKIP == 2) {
      const int Ws = 2 * WOUT;
      f16x8 as = *(const f16x8*)(sb + ((size_t)(2 * y) * Ws + 2 * (x0 + n)) * 32 + q * 8);
      acc0 = __builtin_amdgcn_mfma_f32_16x16x32_f16(wsf0, as, acc0, 0, 0, 0);
      acc1 = __builtin_amdgcn_mfma_f32_16x16x32_f16(wsf1, as, acc1, 0, 0, 0);
    }
    size_t px = (size_t)y * WOUT + x0 + n;
    f16x4 s0, s1;
    if (SKIP == 1) {
      s0 = *(const f16x4*)(sb + px * 32 + q * 4);
      s1 = *(const f16x4*)(sb + px * 32 + 16 + q * 4);
    }
    f16x4 o0, o1;
#pragma unroll
    for (int r = 0; r < 4; r++) {
      float v0 = acc0[r] + bb0[r];
      float v1 = acc1[r] + bb1[r];
      if (SKIP == 1) { v0 += (float)s0[r]; v1 += (float)s1[r]; }
      o0[r] = (f16)v0; o1[r] = (f16)v1;
      sm0v[r] += v0; sq0v[r] += v0 * v0;
      sm1v[r] += v1; sq1v[r] += v1 * v1;
    }
    *(f16x4*)(ro + px * 32 + q * 4) = o0;
    *(f16x4*)(ro + px * 32 + 16 + q * 4) = o1;
  }
  if (ostats) {
#pragma unroll
    for (int r = 0; r < 4; r++) {
#pragma unroll
      for (int d = 1; d < 16; d <<= 1) {
        sm0v[r] += __shfl_xor(sm0v[r], d);
        sq0v[r] += __shfl_xor(sq0v[r], d);
        sm1v[r] += __shfl_xor(sm1v[r], d);
        sq1v[r] += __shfl_xor(sq1v[r], d);
      }
    }
    if (n == 0) {
#pragma unroll
      for (int r = 0; r < 4; r++) {
        atomicAdd(&ostats[b * 32 + q * 4 + r].x, sm0v[r]);
        atomicAdd(&ostats[b * 32 + q * 4 + r].y, sq0v[r]);
        atomicAdd(&ostats[b * 32 + 16 + q * 4 + r].x, sm1v[r]);
        atomicAdd(&ostats[b * 32 + 16 + q * 4 + r].y, sq1v[r]);
      }
    }
  }
}

// ---------------- MFMA 7x7 s2 conv1: LDS-staged fused norm+pack -----------
// Block: 4 output rows x full 128 cols. Transposed MFMA output stores.
__global__ __launch_bounds__(256) void conv7(
    const float* __restrict__ x, const float2* __restrict__ SPx8,
    const f16* __restrict__ wp, const float* __restrict__ bias,
    f16* __restrict__ Rout, float2* __restrict__ ostats) {
  __shared__ f16 lds[13 * 131 * 8];
  const int t = threadIdx.x, w = t >> 6, l = t & 63;
  const int n = l & 15, q = l >> 4;
  const int b = blockIdx.z;
  const int yb = blockIdx.x * 4;
  const float* Xb = x + (size_t)b * 3 * 65536;
  float mn[3], rs[3];
#pragma unroll
  for (int ci = 0; ci < 3; ci++) {
    float sx = 0.f, sxx = 0.f;
#pragma unroll
    for (int c = 0; c < 8; c++) {
      float2 v = SPx8[(b * 3 + ci) * 8 + c];
      sx += v.x; sxx += v.y;
    }
    mn[ci] = sx * (1.f / 65536.f);
    rs[ci] = rsqrtf(sxx * (1.f / 65536.f) - mn[ci] * mn[ci] + INORM_EPS);
  }
  f16x8 wf[14];
#pragma unroll
  for (int i = 0; i < 14; i++) wf[i] = *(const f16x8*)(wp + i * 512 + l * 8);
  float bb0[4], bb1[4];
#pragma unroll
  for (int r = 0; r < 4; r++) {
    bb0[r] = bias[q * 4 + r];
    bb1[r] = bias[16 + q * 4 + r];
  }

  // ---- stage: 13 rows x 262 cols, coalesced, normalized, zero halo ----
  for (int idx = t; idx < 13 * 262; idx += 256) {
    int ri = idx / 262, cl = idx - ri * 262;
    int row = 2 * yb - 3 + ri, col = cl - 3;
    bool ok = ((unsigned)row < 256u) && ((unsigned)col < 256u);
    f16x4 v = {};
    if (ok) {
      const float* p = Xb + (size_t)row * 256 + col;
      v[0] = (f16)((p[0] - mn[0]) * rs[0]);
      v[1] = (f16)((p[65536] - mn[1]) * rs[1]);
      v[2] = (f16)((p[131072] - mn[2]) * rs[2]);
    }
    *(f16x4*)(lds + ((ri * 131 + (cl >> 1)) * 8) + (cl & 1) * 4) = v;
  }
  __syncthreads();

  float sm0v[4] = {}, sq0v[4] = {}, sm1v[4] = {}, sq1v[4] = {};
  f16* ro = Rout + (size_t)b * 16384 * 32;

#pragma unroll
  for (int seg = 0; seg < 2; seg++) {
    const int tx = w + seg * 4;
    const int x0 = tx * 16;
    const int u = x0 + n + q;  // lds col-pair index for this lane
#pragma unroll
    for (int i = 0; i < 4; i++) {
      int y = yb + i;
      f32x4 acc0 = {0.f, 0.f, 0.f, 0.f}, acc1 = {0.f, 0.f, 0.f, 0.f};
#pragma unroll
      for (int ky = 0; ky < 7; ky++) {
        f16x8 a = *(const f16x8*)(lds + ((2 * i + ky) * 131 + u) * 8);
        acc0 = __builtin_amdgcn_mfma_f32_16x16x32_f16(wf[2 * ky], a, acc0, 0, 0, 0);
        acc1 = __builtin_amdgcn_mfma_f32_16x16x32_f16(wf[2 * ky + 1], a, acc1, 0, 0, 0);
      }
      size_t px = (size_t)y * 128 + x0 + n;
      f16x4 o0, o1;
#pragma unroll
      for (int r = 0; r < 4; r++) {
        float v0 = acc0[r] + bb0[r];
        float v1 = acc1[r] + bb1[r];
        o0[r] = (f16)v0; o1[r] = (f16)v1;
        sm0v[r] += v0; sq0v[r] += v0 * v0;
        sm1v[r] += v1; sq1v[r] += v1 * v1;
      }
      *(f16x4*)(ro + px * 32 + q * 4) = o0;
      *(f16x4*)(ro + px * 32 + 16 + q * 4) = o1;
    }
  }
#pragma unroll
  for (int r = 0; r < 4; r++) {
#pragma unroll
    for (int d = 1; d < 16; d <<= 1) {
      sm0v[r] += __shfl_xor(sm0v[r], d);
      sq0v[r] += __shfl_xor(sq0v[r], d);
      sm1v[r] += __shfl_xor(sm1v[r], d);
      sq1v[r] += __shfl_xor(sq1v[r], d);
    }
  }
  if (n == 0) {
#pragma unroll
    for (int r = 0; r < 4; r++) {
      atomicAdd(&ostats[b * 32 + q * 4 + r].x, sm0v[r]);
      atomicAdd(&ostats[b * 32 + q * 4 + r].y, sq0v[r]);
      atomicAdd(&ostats[b * 32 + 16 + q * 4 + r].x, sm1v[r]);
      atomicAdd(&ostats[b * 32 + 16 + q * 4 + r].y, sq1v[r]);
    }
  }
}

// ---------------- tail stage 1: gates G[o][b] -----------------------------
__global__ __launch_bounds__(256) void gates_kernel(
    const float* __restrict__ text, const float* __restrict__ attn_w,
    const float* __restrict__ attn_b, float* __restrict__ G) {
  __shared__ float s_text[64 * 257];
  __shared__ float s_w[16 * 256];
  const int t = threadIdx.x, wv = t >> 6, lane = t & 63;
  const int o0 = blockIdx.x * 16;
  for (int d = t; d < 16384; d += 256) {
    int b = d >> 8, k = d & 255;
    s_text[b * 257 + k] = text[d];
  }
  for (int d = t; d < 4096; d += 256) s_w[d] = attn_w[(size_t)o0 * 256 + d];
  __syncthreads();
  float acc[4];
#pragma unroll
  for (int j = 0; j < 4; j++) acc[j] = attn_b[o0 + wv * 4 + j];
  for (int k = 0; k < 256; k++) {
    float tv = s_text[lane * 257 + k];
#pragma unroll
    for (int j = 0; j < 4; j++) acc[j] = fmaf(s_w[(wv * 4 + j) * 256 + k], tv, acc[j]);
  }
#pragma unroll
  for (int j = 0; j < 4; j++) {
    int o = o0 + wv * 4 + j;
    G[o * 64 + lane] = 1.f / (1.f + __expf(-acc[j]));
  }
}

// ---------------- tail stage 2: scores -> softmax -> amapT ----------------
__global__ __launch_bounds__(256) void scores_kernel(
    const f16* __restrict__ feat, const float* __restrict__ G,
    float* __restrict__ amapT) {
  __shared__ float s_feat[256 * 33];
  __shared__ float s_gate[1280];
  __shared__ float s_scores[5 * 32];
  __shared__ float s_probs[5 * 32];
  const int b = blockIdx.x;
  const int t = threadIdx.x;

  for (int i = t; i < 8192; i += 256)
    s_feat[(i >> 5) * 33 + (i & 31)] = (float)feat[(size_t)b * 8192 + i];
  for (int i = t; i < 1280; i += 256) s_gate[i] = G[i * 64 + b];
  __syncthreads();

  if (t < 160) {
    int h = t >> 5, c = t & 31;
    float acc = 0.f;
    for (int ij = 0; ij < 256; ij++) acc += s_gate[h * 256 + ij] * s_feat[ij * 33 + c];
    s_scores[t] = acc;
  }
  __syncthreads();

  if (t < 5) {
    float mx = -1e30f;
    for (int c = 0; c < 32; c++) mx = fmaxf(mx, s_scores[t * 32 + c]);
    float sum = 0.f;
    for (int c = 0; c < 32; c++) {
      float e = __expf(s_scores[t * 32 + c] - mx);
      s_probs[t * 32 + c] = e;
      sum += e;
    }
    float inv = 1.f / sum;
    for (int c = 0; c < 32; c++) s_probs[t * 32 + c] *= inv;
  }
  __syncthreads();

  for (int h = 0; h < 5; h++) {
    float acc = 0.f;
    for (int c = 0; c < 32; c++) acc += s_probs[h * 32 + c] * s_feat[t * 33 + c];
    amapT[(h * 256 + t) * 64 + b] = acc;
  }
}

// ---------------- tail stage 3: final linear, k split across waves --------
__global__ __launch_bounds__(256) void final_kernel(
    const float* __restrict__ amapT, const float* __restrict__ final_w,
    const float* __restrict__ final_b, float* __restrict__ out) {
  __shared__ float s_w[4 * 1280];
  __shared__ float s_red[4][4][64];
  const int t = threadIdx.x, wv = t >> 6, lane = t & 63;
  const int e0 = blockIdx.x * 4;
  for (int d = t; d < 5120; d += 256) s_w[d] = final_w[(size_t)e0 * 1280 + d];
  __syncthreads();
  const int k0 = wv * 320;
  float acc[4] = {0.f, 0.f, 0.f, 0.f};
  for (int k = k0; k < k0 + 320; k++) {
    float av = amapT[k * 64 + lane];
#pragma unroll
    for (int e = 0; e < 4; e++) acc[e] = fmaf(s_w[e * 1280 + k], av, acc[e]);
  }
#pragma unroll
  for (int e = 0; e < 4; e++) s_red[wv][e][lane] = acc[e];
  __syncthreads();
  if (wv == 0) {
#pragma unroll
    for (int e = 0; e < 4; e++) {
      float v = s_red[0][e][lane] + s_red[1][e][lane] + s_red[2][e][lane] +
                s_red[3][e][lane] + final_b[e0 + e];
      out[(size_t)lane * 512 + e0 + e] = v;
    }
  }
}

// -------------------------------------------------------------------------
extern "C" void kernel_launch(void* const* d_in, const int* in_sizes, int n_in,
                              void* d_out, int out_size, void* d_ws, size_t ws_size,
                              hipStream_t stream) {
  (void)in_sizes; (void)n_in; (void)out_size; (void)ws_size;
  const float* x       = (const float*)d_in[0];
  const float* text    = (const float*)d_in[1];
  const float* conv1_w = (const float*)d_in[2];
  const float* conv1_b = (const float*)d_in[3];
  const float* rbs_w1  = (const float*)d_in[4];
  const float* rbs_b1  = (const float*)d_in[5];
  const float* rbs_w2  = (const float*)d_in[6];
  const float* rbs_b2  = (const float*)d_in[7];
  const float* rbs_ws  = (const float*)d_in[8];
  const float* rbs_bs  = (const float*)d_in[9];
  const float* rb_w1   = (const float*)d_in[10];
  const float* rb_b1   = (const float*)d_in[11];
  const float* rb_w2   = (const float*)d_in[12];
  const float* rb_b2   = (const float*)d_in[13];
  const float* attn_w  = (const float*)d_in[14];
  const float* attn_b  = (const float*)d_in[15];
  const float* final_w = (const float*)d_in[16];
  const float* final_b = (const float*)d_in[17];
  float* out = (float*)d_out;

  char* wsb = (char*)d_ws;
  float2* SPx8 = (float2*)(wsb + 0);          // 1536 float2 (stats partials)
  f16*   R128 = (f16*)(wsb + 35145728);       // 67,108,864
  f16*   R64a = (f16*)(wsb + 102254592);      // 16,777,216
  f16*   R64b = (f16*)(wsb + 119031808);
  f16*   R64c = (f16*)(wsb + 135809024);
  f16*   R32a = (f16*)(wsb + 152586240);      // 4,194,304
  f16*   R32b = (f16*)(wsb + 156780544);
  f16*   R32c = (f16*)(wsb + 160974848);
  f16*   R16a = (f16*)(wsb + 165169152);      // 1,048,576
  f16*   R16b = (f16*)(wsb + 166217728);
  float2* SP  = (float2*)(wsb + 167266304);   // 10*2048 float2
  f16*   wp3  = (f16*)(wsb + 167431680);      // 10*9216
  f16*   wp1  = (f16*)(wsb + 167616000);      // 3*1024
  f16*   wp7  = (f16*)(wsb + 167622144);      // 7168
  float* G     = (float*)(wsb + 167636480);   // 1280*64
  float* amapT = (float*)(wsb + 167964160);   // 1280*64
  float2* SP0 = SP + 0 * 2048;
  float2* SP1 = SP + 1 * 2048;
  float2* SP2 = SP + 2 * 2048;
  float2* SP3 = SP + 3 * 2048;
  float2* SP4 = SP + 4 * 2048;
  float2* SP5 = SP + 5 * 2048;
  float2* SP6 = SP + 6 * 2048;
  float2* SP7 = SP + 7 * 2048;
  float2* SP8 = SP + 8 * 2048;
  float2* SP9 = SP + 9 * 2048;

  // merged prep (zero SP, pack weights) + input stats partials
  prep_stats<<<2016, 256, 0, stream>>>(rbs_w1, rbs_w2, rb_w1, rb_w2, rbs_ws,
                                       conv1_w, x, SP, wp3, wp1, wp7, SPx8);

  // conv1: 7x7 s2, 3->32, 256^2 -> 128^2 (LDS-staged, 4 rows full width)
  conv7<<<dim3(32, 1, 64), 256, 0, stream>>>(x, SPx8, wp7, conv1_b, R128, SP0);

  // rbs0: 128^2 -> 64^2
  conv3n<128, 2, 0, 4><<<dim3(16, 1, 64), 256, 0, stream>>>(
      R128, SP0, 1.f / 16384.f, wp3, rbs_b1, nullptr, nullptr, nullptr, R64a, SP1);
  conv3r<64, 2, 8><<<dim3(8, 1, 64), 256, 0, stream>>>(
      R64a, SP1, 1.f / 4096.f, wp3 + 3 * 9216, rbs_b2, rbs_bs, R128, wp1, R64b, SP2);

  // rb0: 64^2 plain resblock (identity = R64b)
  conv3r<64, 0, 8><<<dim3(8, 1, 64), 256, 0, stream>>>(
      R64b, SP2, 1.f / 4096.f, wp3 + 6 * 9216, rb_b1, nullptr, nullptr, nullptr, R64c, SP3);
  conv3r<64, 1, 8><<<dim3(8, 1, 64), 256, 0, stream>>>(
      R64c, SP3, 1.f / 4096.f, wp3 + 8 * 9216, rb_b2, nullptr, R64b, nullptr, R64a, SP4);

  // rbs1: 64^2 -> 32^2 (skip src = R64a)
  conv3n<64, 2, 0, 4><<<dim3(8, 1, 64), 256, 0, stream>>>(
      R64a, SP4, 1.f / 4096.f, wp3 + 1 * 9216, rbs_b1 + 32, nullptr, nullptr, nullptr, R32a, SP5);
  conv3r<32, 2, 8><<<dim3(4, 1, 64), 256, 0, stream>>>(
      R32a, SP5, 1.f / 1024.f, wp3 + 4 * 9216, rbs_b2 + 32, rbs_bs + 32, R64a, wp1 + 1024, R32b, SP6);

  // rb1: 32^2 plain resblock (identity = R32b)
  conv3r<32, 0, 8><<<dim3(4, 1, 64), 256, 0, stream>>>(
      R32b, SP6, 1.f / 1024.f, wp3 + 7 * 9216, rb_b1 + 32, nullptr, nullptr, nullptr, R32c, SP7);
  conv3r<32, 1, 8><<<dim3(4, 1, 64), 256, 0, stream>>>(
      R32c, SP7, 1.f / 1024.f, wp3 + 9 * 9216, rb_b2 + 32, nullptr, R32b, nullptr, R32a, SP8);

  // rbs2: 32^2 -> 16^2 (skip src = R32a)
  conv3n<32, 2, 0, 8><<<dim3(2, 1, 64), 256, 0, stream>>>(
      R32a, SP8, 1.f / 1024.f, wp3 + 2 * 9216, rbs_b1 + 64, nullptr, nullptr, nullptr, R16a, SP9);
  conv3n<16, 1, 2, 8><<<dim3(2, 1, 64), 256, 0, stream>>>(
      R16a, SP9, 1.f / 256.f, wp3 + 5 * 9216, rbs_b2 + 64, rbs_bs + 64, R32a, wp1 + 2048, R16b, nullptr);

  // attention tail
  gates_kernel<<<80, 256, 0, stream>>>(text, attn_w, attn_b, G);
  scores_kernel<<<64, 256, 0, stream>>>(R16b, G, amapT);
  final_kernel<<<128, 256, 0, stream>>>(amapT, final_w, final_b, out);
}

// Round 8
// 313.163 us; speedup vs baseline: 1.4941x; 1.4941x over previous
//
#include <hip/hip_runtime.h>
#include <cstdint>
#include <cstddef>

#define INORM_EPS 1e-5f

typedef _Float16 f16;
typedef f16 f16x8 __attribute__((ext_vector_type(8)));
typedef f16 f16x4 __attribute__((ext_vector_type(4)));
typedef float f32x4 __attribute__((ext_vector_type(4)));

// ------- merged prep (zero SP, pack weights) + input stats partials -------
__global__ __launch_bounds__(256) void prep_stats(
    const float* __restrict__ rbs_w1, const float* __restrict__ rbs_w2,
    const float* __restrict__ rb_w1, const float* __restrict__ rb_w2,
    const float* __restrict__ rbs_ws, const float* __restrict__ conv1_w,
    const float* __restrict__ x, float2* __restrict__ SP,
    f16* __restrict__ wp3, f16* __restrict__ wp1, f16* __restrict__ wp7,
    float2* __restrict__ SPx8) {
  const int bx = blockIdx.x;
  if (bx >= 480) {
    const int g = bx - 480;
    const int map = g >> 3, chunk = g & 7;
    const float4* p = (const float4*)(x + (size_t)map * 65536 + (size_t)chunk * 8192);
    float s = 0.f, ss = 0.f;
    for (int i = threadIdx.x; i < 2048; i += 256) {
      float4 v = p[i];
      s += v.x + v.y + v.z + v.w;
      ss += v.x * v.x + v.y * v.y + v.z * v.z + v.w * v.w;
    }
    __shared__ float r0[256], r1[256];
    r0[threadIdx.x] = s;
    r1[threadIdx.x] = ss;
    __syncthreads();
    for (int off = 128; off > 0; off >>= 1) {
      if ((int)threadIdx.x < off) {
        r0[threadIdx.x] += r0[threadIdx.x + off];
        r1[threadIdx.x] += r1[threadIdx.x + off];
      }
      __syncthreads();
    }
    if (threadIdx.x == 0) SPx8[map * 8 + chunk] = make_float2(r0[0], r1[0]);
    return;
  }
  int i = bx * 256 + threadIdx.x;
  if (i < 20480) { SP[i] = make_float2(0.f, 0.f); return; }
  i -= 20480;
  if (i < 92160) {  // [mat][9 taps][2 halves][64 lanes][8] ; B-frag layout
    int mat = i / 9216, r = i % 9216;
    int p = r >> 10, f = (r >> 9) & 1, l = (r >> 3) & 63, j = r & 7;
    int co = f * 16 + (l & 15), ci = (l >> 4) * 8 + j;
    const float* src; int m;
    if (mat < 3) { src = rbs_w1; m = mat; }
    else if (mat < 6) { src = rbs_w2; m = mat - 3; }
    else if (mat < 8) { src = rb_w1; m = mat - 6; }
    else { src = rb_w2; m = mat - 8; }
    wp3[i] = (f16)src[m * 9216 + co * 288 + ci * 9 + p];
    return;
  }
  i -= 92160;
  if (i < 3072) {
    int mat = i / 1024, r = i % 1024;
    int f = r >> 9, l = (r >> 3) & 63, j = r & 7;
    wp1[i] = (f16)rbs_ws[mat * 1024 + (f * 16 + (l & 15)) * 32 + (l >> 4) * 8 + j];
    return;
  }
  i -= 3072;
  if (i >= 7168) return;
  int ky = i >> 10, f = (i >> 9) & 1, l = (i >> 3) & 63, j = i & 7;
  int k = (l >> 4) * 8 + j, kx = k >> 2, ci = k & 3;
  float v = 0.f;
  if (kx < 7 && ci < 3) v = conv1_w[(f * 16 + (l & 15)) * 147 + ci * 49 + ky * 7 + kx];
  wp7[i] = (f16)v;
}

// ---------------- MFMA 3x3 stride-1 conv, rolling row window --------------
// 2-deep row prefetch: rows i+2 and i+3 in flight (6 outstanding loads).
template <int W, int SKIP, int RPB>
__global__ __launch_bounds__(256) void conv3r(
    const f16* __restrict__ Rin, const float2* __restrict__ SPin, float inv_hw,
    const f16* __restrict__ wp, const float* __restrict__ bias,
    const float* __restrict__ bias2, const f16* __restrict__ skip,
    const f16* __restrict__ wps, f16* __restrict__ Rout,
    float2* __restrict__ ostats) {
  constexpr int TPR = W / 16;
  constexpr int LEN = (RPB * TPR) / 4;
  const int t = threadIdx.x, w = t >> 6, l = t & 63;
  const int n = l & 15, q = l >> 4;
  const int b = blockIdx.z;
  const int tx = w % TPR;
  const int y0 = blockIdx.x * RPB + (w / TPR) * LEN;
  const int x = (tx << 4) + n;
  const f16* Rb = Rin + (size_t)b * W * W * 32;

  f16x8 sc, sh;
#pragma unroll
  for (int j = 0; j < 8; j++) {
    float2 s = SPin[b * 32 + q * 8 + j];
    float mean = s.x * inv_hw;
    float rstd = rsqrtf(s.y * inv_hw - mean * mean + INORM_EPS);
    sc[j] = (f16)rstd;
    sh[j] = (f16)(-mean * rstd);
  }

  f16x8 wf[18];
#pragma unroll
  for (int i = 0; i < 18; i++) wf[i] = *(const f16x8*)(wp + i * 512 + l * 8);
  f16x8 wsf0, wsf1;
  if (SKIP == 2) {
    wsf0 = *(const f16x8*)(wps + l * 8);
    wsf1 = *(const f16x8*)(wps + 512 + l * 8);
  }
  float b0 = bias[n], b1 = bias[16 + n];
  if (SKIP == 2) { b0 += bias2[n]; b1 += bias2[16 + n]; }

  f16* ro = Rout + (size_t)b * W * W * 32;
  const f16* sb = skip ? skip + (size_t)b * (SKIP == 2 ? 4 : 1) * W * W * 32 : nullptr;

  bool okc[3];
#pragma unroll
  for (int kx = 0; kx < 3; kx++) okc[kx] = (unsigned)(x + kx - 1) < (unsigned)W;

  auto rowload = [&](int gy, f16x8* dst) {
    int gyc = min(max(gy, 0), W - 1);
#pragma unroll
    for (int kx = 0; kx < 3; kx++) {
      int gxc = min(max(x + kx - 1, 0), W - 1);
      dst[kx] = *(const f16x8*)(Rb + ((size_t)gyc * W + gxc) * 32 + q * 8);
    }
  };
  auto rownorm = [&](int gy, const f16x8* src, f16x8* dst) {
    bool okr = (unsigned)gy < (unsigned)W;
#pragma unroll
    for (int kx = 0; kx < 3; kx++) {
      f16x8 v = src[kx] * sc + sh;
#pragma unroll
      for (int e = 0; e < 8; e++) v[e] = v[e] > (f16)0 ? v[e] : (f16)0;
      f16x8 z = {};
      dst[kx] = (okr && okc[kx]) ? v : z;
    }
  };

  float sm0 = 0.f, sq0 = 0.f, sm1 = 0.f, sq1 = 0.f;
  f16x8 win[9];
  f16x8 pf[2][3];
#pragma unroll
  for (int jj = 0; jj < 3; jj++) rowload(y0 + jj - 1, &win[jj * 3]);
  if (LEN > 1) rowload(y0 + 2, pf[0]);
#pragma unroll
  for (int jj = 0; jj < 3; jj++) rownorm(y0 + jj - 1, &win[jj * 3], &win[jj * 3]);

#pragma unroll
  for (int i = 0; i < LEN; i++) {
    int y = y0 + i;
    if (i + 2 < LEN) rowload(y0 + i + 3, pf[(i + 1) & 1]);
    f32x4 acc0 = {0.f, 0.f, 0.f, 0.f}, acc1 = {0.f, 0.f, 0.f, 0.f};
#pragma unroll
    for (int ky = 0; ky < 3; ky++) {
      int slot = (i + ky) % 3;
#pragma unroll
      for (int kx = 0; kx < 3; kx++) {
        f16x8 a = win[slot * 3 + kx];
        acc0 = __builtin_amdgcn_mfma_f32_16x16x32_f16(a, wf[2 * (ky * 3 + kx)], acc0, 0, 0, 0);
        acc1 = __builtin_amdgcn_mfma_f32_16x16x32_f16(a, wf[2 * (ky * 3 + kx) + 1], acc1, 0, 0, 0);
      }
    }
    if (SKIP == 2) {
      const int Ws = 2 * W;
      f16x8 as = *(const f16x8*)(sb + ((size_t)(2 * y) * Ws + 2 * x) * 32 + q * 8);
      acc0 = __builtin_amdgcn_mfma_f32_16x16x32_f16(as, wsf0, acc0, 0, 0, 0);
      acc1 = __builtin_amdgcn_mfma_f32_16x16x32_f16(as, wsf1, acc1, 0, 0, 0);
    }
#pragma unroll
    for (int r = 0; r < 4; r++) {
      size_t px = (size_t)y * W + (tx << 4) + q * 4 + r;
      float v0 = acc0[r] + b0;
      float v1 = acc1[r] + b1;
      if (SKIP == 1) {
        v0 += (float)sb[px * 32 + n];
        v1 += (float)sb[px * 32 + 16 + n];
      }
      ro[px * 32 + n] = (f16)v0;
      ro[px * 32 + 16 + n] = (f16)v1;
      sm0 += v0; sq0 += v0 * v0;
      sm1 += v1; sq1 += v1 * v1;
    }
    if (i + 1 < LEN) rownorm(y0 + i + 2, pf[i & 1], &win[(i % 3) * 3]);
  }
  if (ostats) {
    sm0 += __shfl_xor(sm0, 16); sm0 += __shfl_xor(sm0, 32);
    sq0 += __shfl_xor(sq0, 16); sq0 += __shfl_xor(sq0, 32);
    sm1 += __shfl_xor(sm1, 16); sm1 += __shfl_xor(sm1, 32);
    sq1 += __shfl_xor(sq1, 16); sq1 += __shfl_xor(sq1, 32);
    if (l < 16) {
      atomicAdd(&ostats[b * 32 + n].x, sm0);
      atomicAdd(&ostats[b * 32 + n].y, sq0);
      atomicAdd(&ostats[b * 32 + 16 + n].x, sm1);
      atomicAdd(&ostats[b * 32 + 16 + n].y, sq1);
    }
  }
}

// ---------------- MFMA 3x3 conv (pipelined units): stride-2 and 16x16 -----
// 2-deep unit prefetch via rotating register buffers (static indices).
template <int WIN, int STRIDE, int SKIP, int RPB>
__global__ __launch_bounds__(256) void conv3n(
    const f16* __restrict__ Rin, const float2* __restrict__ SPin, float inv_hw,
    const f16* __restrict__ wp, const float* __restrict__ bias,
    const float* __restrict__ bias2, const f16* __restrict__ skip,
    const f16* __restrict__ wps, f16* __restrict__ Rout,
    float2* __restrict__ ostats) {
  constexpr int WOUT = WIN / STRIDE;
  constexpr int TPR = WOUT / 16;
  constexpr int UNITS = TPR * RPB;
  constexpr int U = UNITS / 4;
  static_assert(U >= 1, "need at least one unit per wave");
  constexpr int NB = (U >= 3) ? 3 : ((U >= 2) ? 2 : 1);
  const int t = threadIdx.x, w = t >> 6, l = t & 63;
  const int n = l & 15, q = l >> 4;
  const int b = blockIdx.z;
  const int yb = blockIdx.x * RPB;
  const f16* Rb = Rin + (size_t)b * WIN * WIN * 32;

  f16x8 sc, sh;
#pragma unroll
  for (int j = 0; j < 8; j++) {
    float2 s = SPin[b * 32 + q * 8 + j];
    float mean = s.x * inv_hw;
    float rstd = rsqrtf(s.y * inv_hw - mean * mean + INORM_EPS);
    sc[j] = (f16)rstd;
    sh[j] = (f16)(-mean * rstd);
  }

  f16x8 wf[18];
#pragma unroll
  for (int i = 0; i < 18; i++) wf[i] = *(const f16x8*)(wp + i * 512 + l * 8);
  f16x8 wsf0, wsf1;
  if (SKIP == 2) {
    wsf0 = *(const f16x8*)(wps + l * 8);
    wsf1 = *(const f16x8*)(wps + 512 + l * 8);
  }
  float b0 = bias[n], b1 = bias[16 + n];
  if (SKIP == 2) { b0 += bias2[n]; b1 += bias2[16 + n]; }

  f16* ro = Rout + (size_t)b * WOUT * WOUT * 32;
  const f16* sb = skip ? skip + (size_t)b * (SKIP == 2 ? 4 : 1) * WOUT * WOUT * 32 : nullptr;

  auto load_u = [&](int u, f16x8* a) {
    int ty = u / TPR, tx = u % TPR;
    int y = yb + ty;
#pragma unroll
    for (int kx = 0; kx < 3; kx++) {
      int gx = STRIDE * ((tx << 4) + n) + kx - 1;
      int gxc = min(max(gx, 0), WIN - 1);
#pragma unroll
      for (int ky = 0; ky < 3; ky++) {
        int gy = STRIDE * y + ky - 1;
        int gyc = min(max(gy, 0), WIN - 1);
        a[ky * 3 + kx] = *(const f16x8*)(Rb + ((size_t)gyc * WIN + gxc) * 32 + q * 8);
      }
    }
  };
  auto norm_u = [&](int u, f16x8* a) {
    int ty = u / TPR, tx = u % TPR;
    int y = yb + ty;
#pragma unroll
    for (int kx = 0; kx < 3; kx++) {
      int gx = STRIDE * ((tx << 4) + n) + kx - 1;
      bool okx = (unsigned)gx < (unsigned)WIN;
#pragma unroll
      for (int ky = 0; ky < 3; ky++) {
        int gy = STRIDE * y + ky - 1;
        bool ok = okx && ((unsigned)gy < (unsigned)WIN);
        f16x8 v = a[ky * 3 + kx] * sc + sh;
#pragma unroll
        for (int e = 0; e < 8; e++) v[e] = v[e] > (f16)0 ? v[e] : (f16)0;
        f16x8 z = {};
        a[ky * 3 + kx] = ok ? v : z;
      }
    }
  };

  float sm0 = 0.f, sq0 = 0.f, sm1 = 0.f, sq1 = 0.f;
  f16x8 buf[NB][9];
  load_u(w, buf[0]);
  if (U > 1) load_u(w + 4, buf[1 % NB]);
#pragma unroll
  for (int i = 0; i < U; i++) {
    int u = w + 4 * i;
    if (i + 2 < U) load_u(u + 8, buf[(i + 2) % NB]);
    f16x8* a = buf[i % NB];
    norm_u(u, a);
    int ty = u / TPR, tx = u % TPR;
    int y = yb + ty, x0 = tx << 4;
    f32x4 acc0 = {0.f, 0.f, 0.f, 0.f}, acc1 = {0.f, 0.f, 0.f, 0.f};
#pragma unroll
    for (int p = 0; p < 9; p++) {
      acc0 = __builtin_amdgcn_mfma_f32_16x16x32_f16(a[p], wf[2 * p], acc0, 0, 0, 0);
      acc1 = __builtin_amdgcn_mfma_f32_16x16x32_f16(a[p], wf[2 * p + 1], acc1, 0, 0, 0);
    }
    if (SKIP == 2) {
      const int Ws = 2 * WOUT;
      f16x8 as = *(const f16x8*)(sb + ((size_t)(2 * y) * Ws + 2 * (x0 + n)) * 32 + q * 8);
      acc0 = __builtin_amdgcn_mfma_f32_16x16x32_f16(as, wsf0, acc0, 0, 0, 0);
      acc1 = __builtin_amdgcn_mfma_f32_16x16x32_f16(as, wsf1, acc1, 0, 0, 0);
    }
#pragma unroll
    for (int r = 0; r < 4; r++) {
      size_t px = (size_t)y * WOUT + x0 + q * 4 + r;
      float v0 = acc0[r] + b0;
      float v1 = acc1[r] + b1;
      if (SKIP == 1) {
        v0 += (float)sb[px * 32 + n];
        v1 += (float)sb[px * 32 + 16 + n];
      }
      ro[px * 32 + n] = (f16)v0;
      ro[px * 32 + 16 + n] = (f16)v1;
      sm0 += v0; sq0 += v0 * v0;
      sm1 += v1; sq1 += v1 * v1;
    }
  }
  if (ostats) {
    sm0 += __shfl_xor(sm0, 16); sm0 += __shfl_xor(sm0, 32);
    sq0 += __shfl_xor(sq0, 16); sq0 += __shfl_xor(sq0, 32);
    sm1 += __shfl_xor(sm1, 16); sm1 += __shfl_xor(sm1, 32);
    sq1 += __shfl_xor(sq1, 16); sq1 += __shfl_xor(sq1, 32);
    if (l < 16) {
      atomicAdd(&ostats[b * 32 + n].x, sm0);
      atomicAdd(&ostats[b * 32 + n].y, sq0);
      atomicAdd(&ostats[b * 32 + 16 + n].x, sm1);
      atomicAdd(&ostats[b * 32 + 16 + n].y, sq1);
    }
  }
}

// ---------------- MFMA 7x7 s2 conv1: LDS-staged, 2-chunk pipelined --------
// Block: 8 output rows, 21-row LDS window (44,016 B -> 3 blocks/CU).
// stage rows 0..12 -> barrier -> issue rows 13..20 global loads into regs
// (overlap with chunk-A compute) -> compute out rows 0..3 -> convert+write
// rows 13..20 -> barrier -> compute out rows 4..7. Same per-element math
// and store pattern as the round-6 kernel => bit-identical output.
__global__ __launch_bounds__(256) void conv7(
    const float* __restrict__ x, const float2* __restrict__ SPx8,
    const f16* __restrict__ wp, const float* __restrict__ bias,
    f16* __restrict__ Rout, float2* __restrict__ ostats) {
  __shared__ f16 lds[21 * 131 * 8];  // 44,016 B
  const int t = threadIdx.x, w = t >> 6, l = t & 63;
  const int n = l & 15, q = l >> 4;
  const int b = blockIdx.z;
  const int yb = blockIdx.x * 8;
  const float* Xb = x + (size_t)b * 3 * 65536;
  float mn[3], rs[3];
#pragma unroll
  for (int ci = 0; ci < 3; ci++) {
    float sx = 0.f, sxx = 0.f;
#pragma unroll
    for (int c = 0; c < 8; c++) {
      float2 v = SPx8[(b * 3 + ci) * 8 + c];
      sx += v.x; sxx += v.y;
    }
    mn[ci] = sx * (1.f / 65536.f);
    rs[ci] = rsqrtf(sxx * (1.f / 65536.f) - mn[ci] * mn[ci] + INORM_EPS);
  }
  f16x8 wf[14];
#pragma unroll
  for (int i = 0; i < 14; i++) wf[i] = *(const f16x8*)(wp + i * 512 + l * 8);
  float b0 = bias[n], b1 = bias[16 + n];

  // ---- stage A: rel rows 0..12 (input rows 2*yb-3 ..), coalesced ----
  for (int idx = t; idx < 13 * 262; idx += 256) {
    int ri = idx / 262, cl = idx - ri * 262;
    int row = 2 * yb - 3 + ri, col = cl - 3;
    bool ok = ((unsigned)row < 256u) && ((unsigned)col < 256u);
    f16x4 v = {};
    if (ok) {
      const float* p = Xb + (size_t)row * 256 + col;
      v[0] = (f16)((p[0] - mn[0]) * rs[0]);
      v[1] = (f16)((p[65536] - mn[1]) * rs[1]);
      v[2] = (f16)((p[131072] - mn[2]) * rs[2]);
    }
    *(f16x4*)(lds + ((ri * 131 + (cl >> 1)) * 8) + (cl & 1) * 4) = v;
  }
  __syncthreads();

  // ---- issue stage-B loads (rel rows 13..20) into registers ----
  // 8*262 = 2096 elems; 9 statically-unrolled iterations (regs, not scratch)
  float ub0[9], ub1[9], ub2[9];
#pragma unroll
  for (int it = 0; it < 9; it++) {
    int idx = t + it * 256;
    int ri = idx / 262, cl = idx - ri * 262;
    int row = 2 * yb + 10 + ri, col = cl - 3;
    bool ok = (idx < 2096) && (row < 256) && ((unsigned)col < 256u);
    const float* p = Xb + (size_t)(ok ? row : 0) * 256 + (ok ? col : 0);
    ub0[it] = p[0];
    ub1[it] = p[65536];
    ub2[it] = p[131072];
  }

  float sm0 = 0.f, sq0 = 0.f, sm1 = 0.f, sq1 = 0.f;
  f16* ro = Rout + (size_t)b * 16384 * 32;

  auto compute4 = [&](int i0) {
#pragma unroll
    for (int seg = 0; seg < 2; seg++) {
      const int tx = w + seg * 4;
      const int x0 = tx * 16;
      const int u = x0 + n + q;  // lds col-pair index for this lane
#pragma unroll
      for (int ii = 0; ii < 4; ii++) {
        int i = i0 + ii;
        int y = yb + i;
        f32x4 acc0 = {0.f, 0.f, 0.f, 0.f}, acc1 = {0.f, 0.f, 0.f, 0.f};
#pragma unroll
        for (int ky = 0; ky < 7; ky++) {
          f16x8 a = *(const f16x8*)(lds + ((2 * i + ky) * 131 + u) * 8);
          acc0 = __builtin_amdgcn_mfma_f32_16x16x32_f16(a, wf[2 * ky], acc0, 0, 0, 0);
          acc1 = __builtin_amdgcn_mfma_f32_16x16x32_f16(a, wf[2 * ky + 1], acc1, 0, 0, 0);
        }
#pragma unroll
        for (int r = 0; r < 4; r++) {
          size_t px = (size_t)y * 128 + x0 + q * 4 + r;
          float v0 = acc0[r] + b0;
          float v1 = acc1[r] + b1;
          ro[px * 32 + n] = (f16)v0;
          ro[px * 32 + 16 + n] = (f16)v1;
          sm0 += v0; sq0 += v0 * v0;
          sm1 += v1; sq1 += v1 * v1;
        }
      }
    }
  };

  // chunk A: out rows yb..yb+3 (lds rel rows 0..12) — B loads in flight
  compute4(0);

  // ---- convert + write stage-B rows (rel 13..20) to LDS ----
#pragma unroll
  for (int it = 0; it < 9; it++) {
    int idx = t + it * 256;
    if (idx < 2096) {
      int ri = idx / 262, cl = idx - ri * 262;
      int row = 2 * yb + 10 + ri, col = cl - 3;
      bool ok = (row < 256) && ((unsigned)col < 256u);
      f16x4 v = {};
      if (ok) {
        v[0] = (f16)((ub0[it] - mn[0]) * rs[0]);
        v[1] = (f16)((ub1[it] - mn[1]) * rs[1]);
        v[2] = (f16)((ub2[it] - mn[2]) * rs[2]);
      }
      *(f16x4*)(lds + (((13 + ri) * 131 + (cl >> 1)) * 8) + (cl & 1) * 4) = v;
    }
  }
  __syncthreads();

  // chunk B: out rows yb+4..yb+7 (lds rel rows 8..20)
  compute4(4);

  sm0 += __shfl_xor(sm0, 16); sm0 += __shfl_xor(sm0, 32);
  sq0 += __shfl_xor(sq0, 16); sq0 += __shfl_xor(sq0, 32);
  sm1 += __shfl_xor(sm1, 16); sm1 += __shfl_xor(sm1, 32);
  sq1 += __shfl_xor(sq1, 16); sq1 += __shfl_xor(sq1, 32);
  if (l < 16) {
    atomicAdd(&ostats[b * 32 + n].x, sm0);
    atomicAdd(&ostats[b * 32 + n].y, sq0);
    atomicAdd(&ostats[b * 32 + 16 + n].x, sm1);
    atomicAdd(&ostats[b * 32 + 16 + n].y, sq1);
  }
}

// ---------------- tail stage 1: gates G[o][b] -----------------------------
__global__ __launch_bounds__(256) void gates_kernel(
    const float* __restrict__ text, const float* __restrict__ attn_w,
    const float* __restrict__ attn_b, float* __restrict__ G) {
  __shared__ float s_text[64 * 257];
  __shared__ float s_w[16 * 256];
  const int t = threadIdx.x, wv = t >> 6, lane = t & 63;
  const int o0 = blockIdx.x * 16;
  for (int d = t; d < 16384; d += 256) {
    int b = d >> 8, k = d & 255;
    s_text[b * 257 + k] = text[d];
  }
  for (int d = t; d < 4096; d += 256) s_w[d] = attn_w[(size_t)o0 * 256 + d];
  __syncthreads();
  float acc[4];
#pragma unroll
  for (int j = 0; j < 4; j++) acc[j] = attn_b[o0 + wv * 4 + j];
  for (int k = 0; k < 256; k++) {
    float tv = s_text[lane * 257 + k];
#pragma unroll
    for (int j = 0; j < 4; j++) acc[j] = fmaf(s_w[(wv * 4 + j) * 256 + k], tv, acc[j]);
  }
#pragma unroll
  for (int j = 0; j < 4; j++) {
    int o = o0 + wv * 4 + j;
    G[o * 64 + lane] = 1.f / (1.f + __expf(-acc[j]));
  }
}

// ---------------- tail stage 2: scores -> softmax -> amapT ----------------
__global__ __launch_bounds__(256) void scores_kernel(
    const f16* __restrict__ feat, const float* __restrict__ G,
    float* __restrict__ amapT) {
  __shared__ float s_feat[256 * 33];
  __shared__ float s_gate[1280];
  __shared__ float s_scores[5 * 32];
  __shared__ float s_probs[5 * 32];
  const int b = blockIdx.x;
  const int t = threadIdx.x;

  for (int i = t; i < 8192; i += 256)
    s_feat[(i >> 5) * 33 + (i & 31)] = (float)feat[(size_t)b * 8192 + i];
  for (int i = t; i < 1280; i += 256) s_gate[i] = G[i * 64 + b];
  __syncthreads();

  if (t < 160) {
    int h = t >> 5, c = t & 31;
    float acc = 0.f;
    for (int ij = 0; ij < 256; ij++) acc += s_gate[h * 256 + ij] * s_feat[ij * 33 + c];
    s_scores[t] = acc;
  }
  __syncthreads();

  if (t < 5) {
    float mx = -1e30f;
    for (int c = 0; c < 32; c++) mx = fmaxf(mx, s_scores[t * 32 + c]);
    float sum = 0.f;
    for (int c = 0; c < 32; c++) {
      float e = __expf(s_scores[t * 32 + c] - mx);
      s_probs[t * 32 + c] = e;
      sum += e;
    }
    float inv = 1.f / sum;
    for (int c = 0; c < 32; c++) s_probs[t * 32 + c] *= inv;
  }
  __syncthreads();

  for (int h = 0; h < 5; h++) {
    float acc = 0.f;
    for (int c = 0; c < 32; c++) acc += s_probs[h * 32 + c] * s_feat[t * 33 + c];
    amapT[(h * 256 + t) * 64 + b] = acc;
  }
}

// ---------------- tail stage 3: final linear, k split across waves --------
__global__ __launch_bounds__(256) void final_kernel(
    const float* __restrict__ amapT, const float* __restrict__ final_w,
    const float* __restrict__ final_b, float* __restrict__ out) {
  __shared__ float s_w[4 * 1280];
  __shared__ float s_red[4][4][64];
  const int t = threadIdx.x, wv = t >> 6, lane = t & 63;
  const int e0 = blockIdx.x * 4;
  for (int d = t; d < 5120; d += 256) s_w[d] = final_w[(size_t)e0 * 1280 + d];
  __syncthreads();
  const int k0 = wv * 320;
  float acc[4] = {0.f, 0.f, 0.f, 0.f};
  for (int k = k0; k < k0 + 320; k++) {
    float av = amapT[k * 64 + lane];
#pragma unroll
    for (int e = 0; e < 4; e++) acc[e] = fmaf(s_w[e * 1280 + k], av, acc[e]);
  }
#pragma unroll
  for (int e = 0; e < 4; e++) s_red[wv][e][lane] = acc[e];
  __syncthreads();
  if (wv == 0) {
#pragma unroll
    for (int e = 0; e < 4; e++) {
      float v = s_red[0][e][lane] + s_red[1][e][lane] + s_red[2][e][lane] +
                s_red[3][e][lane] + final_b[e0 + e];
      out[(size_t)lane * 512 + e0 + e] = v;
    }
  }
}

// -------------------------------------------------------------------------
extern "C" void kernel_launch(void* const* d_in, const int* in_sizes, int n_in,
                              void* d_out, int out_size, void* d_ws, size_t ws_size,
                              hipStream_t stream) {
  (void)in_sizes; (void)n_in; (void)out_size; (void)ws_size;
  const float* x       = (const float*)d_in[0];
  const float* text    = (const float*)d_in[1];
  const float* conv1_w = (const float*)d_in[2];
  const float* conv1_b = (const float*)d_in[3];
  const float* rbs_w1  = (const float*)d_in[4];
  const float* rbs_b1  = (const float*)d_in[5];
  const float* rbs_w2  = (const float*)d_in[6];
  const float* rbs_b2  = (const float*)d_in[7];
  const float* rbs_ws  = (const float*)d_in[8];
  const float* rbs_bs  = (const float*)d_in[9];
  const float* rb_w1   = (const float*)d_in[10];
  const float* rb_b1   = (const float*)d_in[11];
  const float* rb_w2   = (const float*)d_in[12];
  const float* rb_b2   = (const float*)d_in[13];
  const float* attn_w  = (const float*)d_in[14];
  const float* attn_b  = (const float*)d_in[15];
  const float* final_w = (const float*)d_in[16];
  const float* final_b = (const float*)d_in[17];
  float* out = (float*)d_out;

  char* wsb = (char*)d_ws;
  float2* SPx8 = (float2*)(wsb + 0);          // 1536 float2 (stats partials)
  f16*   R128 = (f16*)(wsb + 35145728);       // 67,108,864
  f16*   R64a = (f16*)(wsb + 102254592);      // 16,777,216
  f16*   R64b = (f16*)(wsb + 119031808);
  f16*   R64c = (f16*)(wsb + 135809024);
  f16*   R32a = (f16*)(wsb + 152586240);      // 4,194,304
  f16*   R32b = (f16*)(wsb + 156780544);
  f16*   R32c = (f16*)(wsb + 160974848);
  f16*   R16a = (f16*)(wsb + 165169152);      // 1,048,576
  f16*   R16b = (f16*)(wsb + 166217728);
  float2* SP  = (float2*)(wsb + 167266304);   // 10*2048 float2
  f16*   wp3  = (f16*)(wsb + 167431680);      // 10*9216
  f16*   wp1  = (f16*)(wsb + 167616000);      // 3*1024
  f16*   wp7  = (f16*)(wsb + 167622144);      // 7168
  float* G     = (float*)(wsb + 167636480);   // 1280*64
  float* amapT = (float*)(wsb + 167964160);   // 1280*64
  float2* SP0 = SP + 0 * 2048;
  float2* SP1 = SP + 1 * 2048;
  float2* SP2 = SP + 2 * 2048;
  float2* SP3 = SP + 3 * 2048;
  float2* SP4 = SP + 4 * 2048;
  float2* SP5 = SP + 5 * 2048;
  float2* SP6 = SP + 6 * 2048;
  float2* SP7 = SP + 7 * 2048;
  float2* SP8 = SP + 8 * 2048;
  float2* SP9 = SP + 9 * 2048;

  // merged prep (zero SP, pack weights) + input stats partials
  prep_stats<<<2016, 256, 0, stream>>>(rbs_w1, rbs_w2, rb_w1, rb_w2, rbs_ws,
                                       conv1_w, x, SP, wp3, wp1, wp7, SPx8);

  // conv1: 7x7 s2, 3->32, 256^2 -> 128^2 (LDS-staged, 2-chunk pipelined)
  conv7<<<dim3(16, 1, 64), 256, 0, stream>>>(x, SPx8, wp7, conv1_b, R128, SP0);

  // rbs0: 128^2 -> 64^2
  conv3n<128, 2, 0, 4><<<dim3(16, 1, 64), 256, 0, stream>>>(
      R128, SP0, 1.f / 16384.f, wp3, rbs_b1, nullptr, nullptr, nullptr, R64a, SP1);
  conv3r<64, 2, 8><<<dim3(8, 1, 64), 256, 0, stream>>>(
      R64a, SP1, 1.f / 4096.f, wp3 + 3 * 9216, rbs_b2, rbs_bs, R128, wp1, R64b, SP2);

  // rb0: 64^2 plain resblock (identity = R64b)
  conv3r<64, 0, 8><<<dim3(8, 1, 64), 256, 0, stream>>>(
      R64b, SP2, 1.f / 4096.f, wp3 + 6 * 9216, rb_b1, nullptr, nullptr, nullptr, R64c, SP3);
  conv3r<64, 1, 8><<<dim3(8, 1, 64), 256, 0, stream>>>(
      R64c, SP3, 1.f / 4096.f, wp3 + 8 * 9216, rb_b2, nullptr, R64b, nullptr, R64a, SP4);

  // rbs1: 64^2 -> 32^2 (skip src = R64a)
  conv3n<64, 2, 0, 4><<<dim3(8, 1, 64), 256, 0, stream>>>(
      R64a, SP4, 1.f / 4096.f, wp3 + 1 * 9216, rbs_b1 + 32, nullptr, nullptr, nullptr, R32a, SP5);
  conv3r<32, 2, 8><<<dim3(4, 1, 64), 256, 0, stream>>>(
      R32a, SP5, 1.f / 1024.f, wp3 + 4 * 9216, rbs_b2 + 32, rbs_bs + 32, R64a, wp1 + 1024, R32b, SP6);

  // rb1: 32^2 plain resblock (identity = R32b)
  conv3r<32, 0, 8><<<dim3(4, 1, 64), 256, 0, stream>>>(
      R32b, SP6, 1.f / 1024.f, wp3 + 7 * 9216, rb_b1 + 32, nullptr, nullptr, nullptr, R32c, SP7);
  conv3r<32, 1, 8><<<dim3(4, 1, 64), 256, 0, stream>>>(
      R32c, SP7, 1.f / 1024.f, wp3 + 9 * 9216, rb_b2 + 32, nullptr, R32b, nullptr, R32a, SP8);

  // rbs2: 32^2 -> 16^2 (skip src = R32a)
  conv3n<32, 2, 0, 8><<<dim3(2, 1, 64), 256, 0, stream>>>(
      R32a, SP8, 1.f / 1024.f, wp3 + 2 * 9216, rbs_b1 + 64, nullptr, nullptr, nullptr, R16a, SP9);
  conv3n<16, 1, 2, 8><<<dim3(2, 1, 64), 256, 0, stream>>>(
      R16a, SP9, 1.f / 256.f, wp3 + 5 * 9216, rbs_b2 + 64, rbs_bs + 64, R32a, wp1 + 2048, R16b, nullptr);

  // attention tail
  gates_kernel<<<80, 256, 0, stream>>>(text, attn_w, attn_b, G);
  scores_kernel<<<64, 256, 0, stream>>>(R16b, G, amapT);
  final_kernel<<<128, 256, 0, stream>>>(amapT, final_w, final_b, out);
}

// Round 9
// 311.717 us; speedup vs baseline: 1.5010x; 1.0046x over previous
//
#include <hip/hip_runtime.h>
#include <cstdint>
#include <cstddef>

#define INORM_EPS 1e-5f

typedef _Float16 f16;
typedef f16 f16x8 __attribute__((ext_vector_type(8)));
typedef f16 f16x4 __attribute__((ext_vector_type(4)));
typedef float f32x4 __attribute__((ext_vector_type(4)));

// ------- merged prep (zero SP, pack weights) + input stats partials -------
__global__ __launch_bounds__(256) void prep_stats(
    const float* __restrict__ rbs_w1, const float* __restrict__ rbs_w2,
    const float* __restrict__ rb_w1, const float* __restrict__ rb_w2,
    const float* __restrict__ rbs_ws, const float* __restrict__ conv1_w,
    const float* __restrict__ x, float2* __restrict__ SP,
    f16* __restrict__ wp3, f16* __restrict__ wp1, f16* __restrict__ wp7,
    float2* __restrict__ SPx8) {
  const int bx = blockIdx.x;
  if (bx >= 480) {
    const int g = bx - 480;
    const int map = g >> 3, chunk = g & 7;
    const float4* p = (const float4*)(x + (size_t)map * 65536 + (size_t)chunk * 8192);
    float s = 0.f, ss = 0.f;
    for (int i = threadIdx.x; i < 2048; i += 256) {
      float4 v = p[i];
      s += v.x + v.y + v.z + v.w;
      ss += v.x * v.x + v.y * v.y + v.z * v.z + v.w * v.w;
    }
    __shared__ float r0[256], r1[256];
    r0[threadIdx.x] = s;
    r1[threadIdx.x] = ss;
    __syncthreads();
    for (int off = 128; off > 0; off >>= 1) {
      if ((int)threadIdx.x < off) {
        r0[threadIdx.x] += r0[threadIdx.x + off];
        r1[threadIdx.x] += r1[threadIdx.x + off];
      }
      __syncthreads();
    }
    if (threadIdx.x == 0) SPx8[map * 8 + chunk] = make_float2(r0[0], r1[0]);
    return;
  }
  int i = bx * 256 + threadIdx.x;
  if (i < 20480) { SP[i] = make_float2(0.f, 0.f); return; }
  i -= 20480;
  if (i < 92160) {  // [mat][9 taps][2 halves][64 lanes][8] ; B-frag layout
    int mat = i / 9216, r = i % 9216;
    int p = r >> 10, f = (r >> 9) & 1, l = (r >> 3) & 63, j = r & 7;
    int co = f * 16 + (l & 15), ci = (l >> 4) * 8 + j;
    const float* src; int m;
    if (mat < 3) { src = rbs_w1; m = mat; }
    else if (mat < 6) { src = rbs_w2; m = mat - 3; }
    else if (mat < 8) { src = rb_w1; m = mat - 6; }
    else { src = rb_w2; m = mat - 8; }
    wp3[i] = (f16)src[m * 9216 + co * 288 + ci * 9 + p];
    return;
  }
  i -= 92160;
  if (i < 3072) {
    int mat = i / 1024, r = i % 1024;
    int f = r >> 9, l = (r >> 3) & 63, j = r & 7;
    wp1[i] = (f16)rbs_ws[mat * 1024 + (f * 16 + (l & 15)) * 32 + (l >> 4) * 8 + j];
    return;
  }
  i -= 3072;
  if (i >= 7168) return;
  int ky = i >> 10, f = (i >> 9) & 1, l = (i >> 3) & 63, j = i & 7;
  int k = (l >> 4) * 8 + j, kx = k >> 2, ci = k & 3;
  float v = 0.f;
  if (kx < 7 && ci < 3) v = conv1_w[(f * 16 + (l & 15)) * 147 + ci * 49 + ky * 7 + kx];
  wp7[i] = (f16)v;
}

// ---------------- MFMA 3x3 stride-1 conv, rolling row window --------------
// 3-deep row prefetch: rows i+2, i+3, i+4 in flight (9 outstanding loads).
template <int W, int SKIP, int RPB>
__global__ __launch_bounds__(256) void conv3r(
    const f16* __restrict__ Rin, const float2* __restrict__ SPin, float inv_hw,
    const f16* __restrict__ wp, const float* __restrict__ bias,
    const float* __restrict__ bias2, const f16* __restrict__ skip,
    const f16* __restrict__ wps, f16* __restrict__ Rout,
    float2* __restrict__ ostats) {
  constexpr int TPR = W / 16;
  constexpr int LEN = (RPB * TPR) / 4;
  const int t = threadIdx.x, w = t >> 6, l = t & 63;
  const int n = l & 15, q = l >> 4;
  const int b = blockIdx.z;
  const int tx = w % TPR;
  const int y0 = blockIdx.x * RPB + (w / TPR) * LEN;
  const int x = (tx << 4) + n;
  const f16* Rb = Rin + (size_t)b * W * W * 32;

  f16x8 sc, sh;
#pragma unroll
  for (int j = 0; j < 8; j++) {
    float2 s = SPin[b * 32 + q * 8 + j];
    float mean = s.x * inv_hw;
    float rstd = rsqrtf(s.y * inv_hw - mean * mean + INORM_EPS);
    sc[j] = (f16)rstd;
    sh[j] = (f16)(-mean * rstd);
  }

  f16x8 wf[18];
#pragma unroll
  for (int i = 0; i < 18; i++) wf[i] = *(const f16x8*)(wp + i * 512 + l * 8);
  f16x8 wsf0, wsf1;
  if (SKIP == 2) {
    wsf0 = *(const f16x8*)(wps + l * 8);
    wsf1 = *(const f16x8*)(wps + 512 + l * 8);
  }
  float b0 = bias[n], b1 = bias[16 + n];
  if (SKIP == 2) { b0 += bias2[n]; b1 += bias2[16 + n]; }

  f16* ro = Rout + (size_t)b * W * W * 32;
  const f16* sb = skip ? skip + (size_t)b * (SKIP == 2 ? 4 : 1) * W * W * 32 : nullptr;

  bool okc[3];
#pragma unroll
  for (int kx = 0; kx < 3; kx++) okc[kx] = (unsigned)(x + kx - 1) < (unsigned)W;

  auto rowload = [&](int gy, f16x8* dst) {
    int gyc = min(max(gy, 0), W - 1);
#pragma unroll
    for (int kx = 0; kx < 3; kx++) {
      int gxc = min(max(x + kx - 1, 0), W - 1);
      dst[kx] = *(const f16x8*)(Rb + ((size_t)gyc * W + gxc) * 32 + q * 8);
    }
  };
  auto rownorm = [&](int gy, const f16x8* src, f16x8* dst) {
    bool okr = (unsigned)gy < (unsigned)W;
#pragma unroll
    for (int kx = 0; kx < 3; kx++) {
      f16x8 v = src[kx] * sc + sh;
#pragma unroll
      for (int e = 0; e < 8; e++) v[e] = v[e] > (f16)0 ? v[e] : (f16)0;
      f16x8 z = {};
      dst[kx] = (okr && okc[kx]) ? v : z;
    }
  };

  float sm0 = 0.f, sq0 = 0.f, sm1 = 0.f, sq1 = 0.f;
  f16x8 win[9];
  f16x8 pf[3][3];
#pragma unroll
  for (int jj = 0; jj < 3; jj++) rowload(y0 + jj - 1, &win[jj * 3]);
  if (LEN > 1) rowload(y0 + 2, pf[0]);
  if (LEN > 2) rowload(y0 + 3, pf[1]);
#pragma unroll
  for (int jj = 0; jj < 3; jj++) rownorm(y0 + jj - 1, &win[jj * 3], &win[jj * 3]);

#pragma unroll
  for (int i = 0; i < LEN; i++) {
    int y = y0 + i;
    if (i + 3 < LEN) rowload(y0 + i + 4, pf[(i + 2) % 3]);
    f32x4 acc0 = {0.f, 0.f, 0.f, 0.f}, acc1 = {0.f, 0.f, 0.f, 0.f};
#pragma unroll
    for (int ky = 0; ky < 3; ky++) {
      int slot = (i + ky) % 3;
#pragma unroll
      for (int kx = 0; kx < 3; kx++) {
        f16x8 a = win[slot * 3 + kx];
        acc0 = __builtin_amdgcn_mfma_f32_16x16x32_f16(a, wf[2 * (ky * 3 + kx)], acc0, 0, 0, 0);
        acc1 = __builtin_amdgcn_mfma_f32_16x16x32_f16(a, wf[2 * (ky * 3 + kx) + 1], acc1, 0, 0, 0);
      }
    }
    if (SKIP == 2) {
      const int Ws = 2 * W;
      f16x8 as = *(const f16x8*)(sb + ((size_t)(2 * y) * Ws + 2 * x) * 32 + q * 8);
      acc0 = __builtin_amdgcn_mfma_f32_16x16x32_f16(as, wsf0, acc0, 0, 0, 0);
      acc1 = __builtin_amdgcn_mfma_f32_16x16x32_f16(as, wsf1, acc1, 0, 0, 0);
    }
#pragma unroll
    for (int r = 0; r < 4; r++) {
      size_t px = (size_t)y * W + (tx << 4) + q * 4 + r;
      float v0 = acc0[r] + b0;
      float v1 = acc1[r] + b1;
      if (SKIP == 1) {
        v0 += (float)sb[px * 32 + n];
        v1 += (float)sb[px * 32 + 16 + n];
      }
      ro[px * 32 + n] = (f16)v0;
      ro[px * 32 + 16 + n] = (f16)v1;
      sm0 += v0; sq0 += v0 * v0;
      sm1 += v1; sq1 += v1 * v1;
    }
    if (i + 1 < LEN) rownorm(y0 + i + 2, pf[i % 3], &win[(i % 3) * 3]);
  }
  if (ostats) {
    sm0 += __shfl_xor(sm0, 16); sm0 += __shfl_xor(sm0, 32);
    sq0 += __shfl_xor(sq0, 16); sq0 += __shfl_xor(sq0, 32);
    sm1 += __shfl_xor(sm1, 16); sm1 += __shfl_xor(sm1, 32);
    sq1 += __shfl_xor(sq1, 16); sq1 += __shfl_xor(sq1, 32);
    if (l < 16) {
      atomicAdd(&ostats[b * 32 + n].x, sm0);
      atomicAdd(&ostats[b * 32 + n].y, sq0);
      atomicAdd(&ostats[b * 32 + 16 + n].x, sm1);
      atomicAdd(&ostats[b * 32 + 16 + n].y, sq1);
    }
  }
}

// ---------------- MFMA 3x3 conv (pipelined units): stride-2 and 16x16 -----
// 2-deep unit prefetch via rotating register buffers (static indices).
template <int WIN, int STRIDE, int SKIP, int RPB>
__global__ __launch_bounds__(256) void conv3n(
    const f16* __restrict__ Rin, const float2* __restrict__ SPin, float inv_hw,
    const f16* __restrict__ wp, const float* __restrict__ bias,
    const float* __restrict__ bias2, const f16* __restrict__ skip,
    const f16* __restrict__ wps, f16* __restrict__ Rout,
    float2* __restrict__ ostats) {
  constexpr int WOUT = WIN / STRIDE;
  constexpr int TPR = WOUT / 16;
  constexpr int UNITS = TPR * RPB;
  constexpr int U = UNITS / 4;
  static_assert(U >= 1, "need at least one unit per wave");
  constexpr int NB = (U >= 3) ? 3 : ((U >= 2) ? 2 : 1);
  const int t = threadIdx.x, w = t >> 6, l = t & 63;
  const int n = l & 15, q = l >> 4;
  const int b = blockIdx.z;
  const int yb = blockIdx.x * RPB;
  const f16* Rb = Rin + (size_t)b * WIN * WIN * 32;

  f16x8 sc, sh;
#pragma unroll
  for (int j = 0; j < 8; j++) {
    float2 s = SPin[b * 32 + q * 8 + j];
    float mean = s.x * inv_hw;
    float rstd = rsqrtf(s.y * inv_hw - mean * mean + INORM_EPS);
    sc[j] = (f16)rstd;
    sh[j] = (f16)(-mean * rstd);
  }

  f16x8 wf[18];
#pragma unroll
  for (int i = 0; i < 18; i++) wf[i] = *(const f16x8*)(wp + i * 512 + l * 8);
  f16x8 wsf0, wsf1;
  if (SKIP == 2) {
    wsf0 = *(const f16x8*)(wps + l * 8);
    wsf1 = *(const f16x8*)(wps + 512 + l * 8);
  }
  float b0 = bias[n], b1 = bias[16 + n];
  if (SKIP == 2) { b0 += bias2[n]; b1 += bias2[16 + n]; }

  f16* ro = Rout + (size_t)b * WOUT * WOUT * 32;
  const f16* sb = skip ? skip + (size_t)b * (SKIP == 2 ? 4 : 1) * WOUT * WOUT * 32 : nullptr;

  auto load_u = [&](int u, f16x8* a) {
    int ty = u / TPR, tx = u % TPR;
    int y = yb + ty;
#pragma unroll
    for (int kx = 0; kx < 3; kx++) {
      int gx = STRIDE * ((tx << 4) + n) + kx - 1;
      int gxc = min(max(gx, 0), WIN - 1);
#pragma unroll
      for (int ky = 0; ky < 3; ky++) {
        int gy = STRIDE * y + ky - 1;
        int gyc = min(max(gy, 0), WIN - 1);
        a[ky * 3 + kx] = *(const f16x8*)(Rb + ((size_t)gyc * WIN + gxc) * 32 + q * 8);
      }
    }
  };
  auto norm_u = [&](int u, f16x8* a) {
    int ty = u / TPR, tx = u % TPR;
    int y = yb + ty;
#pragma unroll
    for (int kx = 0; kx < 3; kx++) {
      int gx = STRIDE * ((tx << 4) + n) + kx - 1;
      bool okx = (unsigned)gx < (unsigned)WIN;
#pragma unroll
      for (int ky = 0; ky < 3; ky++) {
        int gy = STRIDE * y + ky - 1;
        bool ok = okx && ((unsigned)gy < (unsigned)WIN);
        f16x8 v = a[ky * 3 + kx] * sc + sh;
#pragma unroll
        for (int e = 0; e < 8; e++) v[e] = v[e] > (f16)0 ? v[e] : (f16)0;
        f16x8 z = {};
        a[ky * 3 + kx] = ok ? v : z;
      }
    }
  };

  float sm0 = 0.f, sq0 = 0.f, sm1 = 0.f, sq1 = 0.f;
  f16x8 buf[NB][9];
  load_u(w, buf[0]);
  if (U > 1) load_u(w + 4, buf[1 % NB]);
#pragma unroll
  for (int i = 0; i < U; i++) {
    int u = w + 4 * i;
    if (i + 2 < U) load_u(u + 8, buf[(i + 2) % NB]);
    f16x8* a = buf[i % NB];
    norm_u(u, a);
    int ty = u / TPR, tx = u % TPR;
    int y = yb + ty, x0 = tx << 4;
    f32x4 acc0 = {0.f, 0.f, 0.f, 0.f}, acc1 = {0.f, 0.f, 0.f, 0.f};
#pragma unroll
    for (int p = 0; p < 9; p++) {
      acc0 = __builtin_amdgcn_mfma_f32_16x16x32_f16(a[p], wf[2 * p], acc0, 0, 0, 0);
      acc1 = __builtin_amdgcn_mfma_f32_16x16x32_f16(a[p], wf[2 * p + 1], acc1, 0, 0, 0);
    }
    if (SKIP == 2) {
      const int Ws = 2 * WOUT;
      f16x8 as = *(const f16x8*)(sb + ((size_t)(2 * y) * Ws + 2 * (x0 + n)) * 32 + q * 8);
      acc0 = __builtin_amdgcn_mfma_f32_16x16x32_f16(as, wsf0, acc0, 0, 0, 0);
      acc1 = __builtin_amdgcn_mfma_f32_16x16x32_f16(as, wsf1, acc1, 0, 0, 0);
    }
#pragma unroll
    for (int r = 0; r < 4; r++) {
      size_t px = (size_t)y * WOUT + x0 + q * 4 + r;
      float v0 = acc0[r] + b0;
      float v1 = acc1[r] + b1;
      if (SKIP == 1) {
        v0 += (float)sb[px * 32 + n];
        v1 += (float)sb[px * 32 + 16 + n];
      }
      ro[px * 32 + n] = (f16)v0;
      ro[px * 32 + 16 + n] = (f16)v1;
      sm0 += v0; sq0 += v0 * v0;
      sm1 += v1; sq1 += v1 * v1;
    }
  }
  if (ostats) {
    sm0 += __shfl_xor(sm0, 16); sm0 += __shfl_xor(sm0, 32);
    sq0 += __shfl_xor(sq0, 16); sq0 += __shfl_xor(sq0, 32);
    sm1 += __shfl_xor(sm1, 16); sm1 += __shfl_xor(sm1, 32);
    sq1 += __shfl_xor(sq1, 16); sq1 += __shfl_xor(sq1, 32);
    if (l < 16) {
      atomicAdd(&ostats[b * 32 + n].x, sm0);
      atomicAdd(&ostats[b * 32 + n].y, sq0);
      atomicAdd(&ostats[b * 32 + 16 + n].x, sm1);
      atomicAdd(&ostats[b * 32 + 16 + n].y, sq1);
    }
  }
}

// ---------------- MFMA 7x7 s2 conv1: LDS-staged, 3-chunk pipelined --------
// Block: 8 output rows, 21-row LDS window (44,016 B).
// stage rel rows 0..8 -> barrier -> {issue rows 9..14 || compute out 0..1}
// -> write B -> {issue rows 15..20} -> barrier -> compute out 2..4 ->
// write C -> barrier -> compute out 5..7. Serial-stage fraction 43% vs
// 62% for the 2-chunk version. Same math+stores => bit-identical output.
__global__ __launch_bounds__(256) void conv7(
    const float* __restrict__ x, const float2* __restrict__ SPx8,
    const f16* __restrict__ wp, const float* __restrict__ bias,
    f16* __restrict__ Rout, float2* __restrict__ ostats) {
  __shared__ f16 lds[21 * 131 * 8];  // 44,016 B
  const int t = threadIdx.x, w = t >> 6, l = t & 63;
  const int n = l & 15, q = l >> 4;
  const int b = blockIdx.z;
  const int yb = blockIdx.x * 8;
  const float* Xb = x + (size_t)b * 3 * 65536;
  float mn[3], rs[3];
#pragma unroll
  for (int ci = 0; ci < 3; ci++) {
    float sx = 0.f, sxx = 0.f;
#pragma unroll
    for (int c = 0; c < 8; c++) {
      float2 v = SPx8[(b * 3 + ci) * 8 + c];
      sx += v.x; sxx += v.y;
    }
    mn[ci] = sx * (1.f / 65536.f);
    rs[ci] = rsqrtf(sxx * (1.f / 65536.f) - mn[ci] * mn[ci] + INORM_EPS);
  }
  f16x8 wf[14];
#pragma unroll
  for (int i = 0; i < 14; i++) wf[i] = *(const f16x8*)(wp + i * 512 + l * 8);
  float b0 = bias[n], b1 = bias[16 + n];

  // ---- stage A: rel rows 0..8 (input rows 2*yb-3 ..), coalesced ----
  for (int idx = t; idx < 9 * 262; idx += 256) {
    int ri = idx / 262, cl = idx - ri * 262;
    int row = 2 * yb - 3 + ri, col = cl - 3;
    bool ok = ((unsigned)row < 256u) && ((unsigned)col < 256u);
    f16x4 v = {};
    if (ok) {
      const float* p = Xb + (size_t)row * 256 + col;
      v[0] = (f16)((p[0] - mn[0]) * rs[0]);
      v[1] = (f16)((p[65536] - mn[1]) * rs[1]);
      v[2] = (f16)((p[131072] - mn[2]) * rs[2]);
    }
    *(f16x4*)(lds + ((ri * 131 + (cl >> 1)) * 8) + (cl & 1) * 4) = v;
  }
  __syncthreads();

  float sm0 = 0.f, sq0 = 0.f, sm1 = 0.f, sq1 = 0.f;
  f16* ro = Rout + (size_t)b * 16384 * 32;

  auto compute_chunk = [&](int i0, int i1) {
#pragma unroll
    for (int seg = 0; seg < 2; seg++) {
      const int tx = w + seg * 4;
      const int x0 = tx * 16;
      const int u = x0 + n + q;  // lds col-pair index for this lane
      for (int i = i0; i < i1; i++) {
        int y = yb + i;
        f32x4 acc0 = {0.f, 0.f, 0.f, 0.f}, acc1 = {0.f, 0.f, 0.f, 0.f};
#pragma unroll
        for (int ky = 0; ky < 7; ky++) {
          f16x8 a = *(const f16x8*)(lds + ((2 * i + ky) * 131 + u) * 8);
          acc0 = __builtin_amdgcn_mfma_f32_16x16x32_f16(a, wf[2 * ky], acc0, 0, 0, 0);
          acc1 = __builtin_amdgcn_mfma_f32_16x16x32_f16(a, wf[2 * ky + 1], acc1, 0, 0, 0);
        }
#pragma unroll
        for (int r = 0; r < 4; r++) {
          size_t px = (size_t)y * 128 + x0 + q * 4 + r;
          float v0 = acc0[r] + b0;
          float v1 = acc1[r] + b1;
          ro[px * 32 + n] = (f16)v0;
          ro[px * 32 + 16 + n] = (f16)v1;
          sm0 += v0; sq0 += v0 * v0;
          sm1 += v1; sq1 += v1 * v1;
        }
      }
    }
  };

  // ---- issue chunk-B loads (rel rows 9..14; input rows 2*yb+6+ri) ----
  // 6*262 = 1572 elems; 7 statically-unrolled iterations
  float ub0[7], ub1[7], ub2[7];
#pragma unroll
  for (int it = 0; it < 7; it++) {
    int idx = t + it * 256;
    int ri = idx / 262, cl = idx - ri * 262;
    int row = 2 * yb + 6 + ri, col = cl - 3;
    bool ok = (idx < 1572) && (row < 256) && ((unsigned)col < 256u);
    const float* p = Xb + (size_t)(ok ? row : 0) * 256 + (ok ? col : 0);
    ub0[it] = p[0];
    ub1[it] = p[65536];
    ub2[it] = p[131072];
  }

  // chunk A compute: out rows 0..1 (rel rows 0..8) — B loads in flight
  compute_chunk(0, 2);

  // ---- convert + write chunk B (rel rows 9..14) ----
#pragma unroll
  for (int it = 0; it < 7; it++) {
    int idx = t + it * 256;
    if (idx < 1572) {
      int ri = idx / 262, cl = idx - ri * 262;
      int row = 2 * yb + 6 + ri, col = cl - 3;
      bool ok = (row < 256) && ((unsigned)col < 256u);
      f16x4 v = {};
      if (ok) {
        v[0] = (f16)((ub0[it] - mn[0]) * rs[0]);
        v[1] = (f16)((ub1[it] - mn[1]) * rs[1]);
        v[2] = (f16)((ub2[it] - mn[2]) * rs[2]);
      }
      *(f16x4*)(lds + (((9 + ri) * 131 + (cl >> 1)) * 8) + (cl & 1) * 4) = v;
    }
  }

  // ---- issue chunk-C loads (rel rows 15..20; input rows 2*yb+12+ri) ----
  float uc0[7], uc1[7], uc2[7];
#pragma unroll
  for (int it = 0; it < 7; it++) {
    int idx = t + it * 256;
    int ri = idx / 262, cl = idx - ri * 262;
    int row = 2 * yb + 12 + ri, col = cl - 3;
    bool ok = (idx < 1572) && (row < 256) && ((unsigned)col < 256u);
    const float* p = Xb + (size_t)(ok ? row : 0) * 256 + (ok ? col : 0);
    uc0[it] = p[0];
    uc1[it] = p[65536];
    uc2[it] = p[131072];
  }
  __syncthreads();

  // chunk B compute: out rows 2..4 (rel rows 4..14) — C loads in flight
  compute_chunk(2, 5);

  // ---- convert + write chunk C (rel rows 15..20) ----
#pragma unroll
  for (int it = 0; it < 7; it++) {
    int idx = t + it * 256;
    if (idx < 1572) {
      int ri = idx / 262, cl = idx - ri * 262;
      int row = 2 * yb + 12 + ri, col = cl - 3;
      bool ok = (row < 256) && ((unsigned)col < 256u);
      f16x4 v = {};
      if (ok) {
        v[0] = (f16)((uc0[it] - mn[0]) * rs[0]);
        v[1] = (f16)((uc1[it] - mn[1]) * rs[1]);
        v[2] = (f16)((uc2[it] - mn[2]) * rs[2]);
      }
      *(f16x4*)(lds + (((15 + ri) * 131 + (cl >> 1)) * 8) + (cl & 1) * 4) = v;
    }
  }
  __syncthreads();

  // chunk C compute: out rows 5..7 (rel rows 10..20)
  compute_chunk(5, 8);

  sm0 += __shfl_xor(sm0, 16); sm0 += __shfl_xor(sm0, 32);
  sq0 += __shfl_xor(sq0, 16); sq0 += __shfl_xor(sq0, 32);
  sm1 += __shfl_xor(sm1, 16); sm1 += __shfl_xor(sm1, 32);
  sq1 += __shfl_xor(sq1, 16); sq1 += __shfl_xor(sq1, 32);
  if (l < 16) {
    atomicAdd(&ostats[b * 32 + n].x, sm0);
    atomicAdd(&ostats[b * 32 + n].y, sq0);
    atomicAdd(&ostats[b * 32 + 16 + n].x, sm1);
    atomicAdd(&ostats[b * 32 + 16 + n].y, sq1);
  }
}

// ---------------- tail stage 1: gates G[o][b] -----------------------------
__global__ __launch_bounds__(256) void gates_kernel(
    const float* __restrict__ text, const float* __restrict__ attn_w,
    const float* __restrict__ attn_b, float* __restrict__ G) {
  __shared__ float s_text[64 * 257];
  __shared__ float s_w[16 * 256];
  const int t = threadIdx.x, wv = t >> 6, lane = t & 63;
  const int o0 = blockIdx.x * 16;
  for (int d = t; d < 16384; d += 256) {
    int b = d >> 8, k = d & 255;
    s_text[b * 257 + k] = text[d];
  }
  for (int d = t; d < 4096; d += 256) s_w[d] = attn_w[(size_t)o0 * 256 + d];
  __syncthreads();
  float acc[4];
#pragma unroll
  for (int j = 0; j < 4; j++) acc[j] = attn_b[o0 + wv * 4 + j];
  for (int k = 0; k < 256; k++) {
    float tv = s_text[lane * 257 + k];
#pragma unroll
    for (int j = 0; j < 4; j++) acc[j] = fmaf(s_w[(wv * 4 + j) * 256 + k], tv, acc[j]);
  }
#pragma unroll
  for (int j = 0; j < 4; j++) {
    int o = o0 + wv * 4 + j;
    G[o * 64 + lane] = 1.f / (1.f + __expf(-acc[j]));
  }
}

// ---------------- tail stage 2: scores -> softmax -> amapT ----------------
__global__ __launch_bounds__(256) void scores_kernel(
    const f16* __restrict__ feat, const float* __restrict__ G,
    float* __restrict__ amapT) {
  __shared__ float s_feat[256 * 33];
  __shared__ float s_gate[1280];
  __shared__ float s_scores[5 * 32];
  __shared__ float s_probs[5 * 32];
  const int b = blockIdx.x;
  const int t = threadIdx.x;

  for (int i = t; i < 8192; i += 256)
    s_feat[(i >> 5) * 33 + (i & 31)] = (float)feat[(size_t)b * 8192 + i];
  for (int i = t; i < 1280; i += 256) s_gate[i] = G[i * 64 + b];
  __syncthreads();

  if (t < 160) {
    int h = t >> 5, c = t & 31;
    float acc = 0.f;
    for (int ij = 0; ij < 256; ij++) acc += s_gate[h * 256 + ij] * s_feat[ij * 33 + c];
    s_scores[t] = acc;
  }
  __syncthreads();

  if (t < 5) {
    float mx = -1e30f;
    for (int c = 0; c < 32; c++) mx = fmaxf(mx, s_scores[t * 32 + c]);
    float sum = 0.f;
    for (int c = 0; c < 32; c++) {
      float e = __expf(s_scores[t * 32 + c] - mx);
      s_probs[t * 32 + c] = e;
      sum += e;
    }
    float inv = 1.f / sum;
    for (int c = 0; c < 32; c++) s_probs[t * 32 + c] *= inv;
  }
  __syncthreads();

  for (int h = 0; h < 5; h++) {
    float acc = 0.f;
    for (int c = 0; c < 32; c++) acc += s_probs[h * 32 + c] * s_feat[t * 33 + c];
    amapT[(h * 256 + t) * 64 + b] = acc;
  }
}

// ---------------- tail stage 3: final linear, k split across waves --------
__global__ __launch_bounds__(256) void final_kernel(
    const float* __restrict__ amapT, const float* __restrict__ final_w,
    const float* __restrict__ final_b, float* __restrict__ out) {
  __shared__ float s_w[4 * 1280];
  __shared__ float s_red[4][4][64];
  const int t = threadIdx.x, wv = t >> 6, lane = t & 63;
  const int e0 = blockIdx.x * 4;
  for (int d = t; d < 5120; d += 256) s_w[d] = final_w[(size_t)e0 * 1280 + d];
  __syncthreads();
  const int k0 = wv * 320;
  float acc[4] = {0.f, 0.f, 0.f, 0.f};
  for (int k = k0; k < k0 + 320; k++) {
    float av = amapT[k * 64 + lane];
#pragma unroll
    for (int e = 0; e < 4; e++) acc[e] = fmaf(s_w[e * 1280 + k], av, acc[e]);
  }
#pragma unroll
  for (int e = 0; e < 4; e++) s_red[wv][e][lane] = acc[e];
  __syncthreads();
  if (wv == 0) {
#pragma unroll
    for (int e = 0; e < 4; e++) {
      float v = s_red[0][e][lane] + s_red[1][e][lane] + s_red[2][e][lane] +
                s_red[3][e][lane] + final_b[e0 + e];
      out[(size_t)lane * 512 + e0 + e] = v;
    }
  }
}

// -------------------------------------------------------------------------
extern "C" void kernel_launch(void* const* d_in, const int* in_sizes, int n_in,
                              void* d_out, int out_size, void* d_ws, size_t ws_size,
                              hipStream_t stream) {
  (void)in_sizes; (void)n_in; (void)out_size; (void)ws_size;
  const float* x       = (const float*)d_in[0];
  const float* text    = (const float*)d_in[1];
  const float* conv1_w = (const float*)d_in[2];
  const float* conv1_b = (const float*)d_in[3];
  const float* rbs_w1  = (const float*)d_in[4];
  const float* rbs_b1  = (const float*)d_in[5];
  const float* rbs_w2  = (const float*)d_in[6];
  const float* rbs_b2  = (const float*)d_in[7];
  const float* rbs_ws  = (const float*)d_in[8];
  const float* rbs_bs  = (const float*)d_in[9];
  const float* rb_w1   = (const float*)d_in[10];
  const float* rb_b1   = (const float*)d_in[11];
  const float* rb_w2   = (const float*)d_in[12];
  const float* rb_b2   = (const float*)d_in[13];
  const float* attn_w  = (const float*)d_in[14];
  const float* attn_b  = (const float*)d_in[15];
  const float* final_w = (const float*)d_in[16];
  const float* final_b = (const float*)d_in[17];
  float* out = (float*)d_out;

  char* wsb = (char*)d_ws;
  float2* SPx8 = (float2*)(wsb + 0);          // 1536 float2 (stats partials)
  f16*   R128 = (f16*)(wsb + 35145728);       // 67,108,864
  f16*   R64a = (f16*)(wsb + 102254592);      // 16,777,216
  f16*   R64b = (f16*)(wsb + 119031808);
  f16*   R64c = (f16*)(wsb + 135809024);
  f16*   R32a = (f16*)(wsb + 152586240);      // 4,194,304
  f16*   R32b = (f16*)(wsb + 156780544);
  f16*   R32c = (f16*)(wsb + 160974848);
  f16*   R16a = (f16*)(wsb + 165169152);      // 1,048,576
  f16*   R16b = (f16*)(wsb + 166217728);
  float2* SP  = (float2*)(wsb + 167266304);   // 10*2048 float2
  f16*   wp3  = (f16*)(wsb + 167431680);      // 10*9216
  f16*   wp1  = (f16*)(wsb + 167616000);      // 3*1024
  f16*   wp7  = (f16*)(wsb + 167622144);      // 7168
  float* G     = (float*)(wsb + 167636480);   // 1280*64
  float* amapT = (float*)(wsb + 167964160);   // 1280*64
  float2* SP0 = SP + 0 * 2048;
  float2* SP1 = SP + 1 * 2048;
  float2* SP2 = SP + 2 * 2048;
  float2* SP3 = SP + 3 * 2048;
  float2* SP4 = SP + 4 * 2048;
  float2* SP5 = SP + 5 * 2048;
  float2* SP6 = SP + 6 * 2048;
  float2* SP7 = SP + 7 * 2048;
  float2* SP8 = SP + 8 * 2048;
  float2* SP9 = SP + 9 * 2048;

  // merged prep (zero SP, pack weights) + input stats partials
  prep_stats<<<2016, 256, 0, stream>>>(rbs_w1, rbs_w2, rb_w1, rb_w2, rbs_ws,
                                       conv1_w, x, SP, wp3, wp1, wp7, SPx8);

  // conv1: 7x7 s2, 3->32, 256^2 -> 128^2 (LDS-staged, 3-chunk pipelined)
  conv7<<<dim3(16, 1, 64), 256, 0, stream>>>(x, SPx8, wp7, conv1_b, R128, SP0);

  // rbs0: 128^2 -> 64^2
  conv3n<128, 2, 0, 4><<<dim3(16, 1, 64), 256, 0, stream>>>(
      R128, SP0, 1.f / 16384.f, wp3, rbs_b1, nullptr, nullptr, nullptr, R64a, SP1);
  conv3r<64, 2, 8><<<dim3(8, 1, 64), 256, 0, stream>>>(
      R64a, SP1, 1.f / 4096.f, wp3 + 3 * 9216, rbs_b2, rbs_bs, R128, wp1, R64b, SP2);

  // rb0: 64^2 plain resblock (identity = R64b)
  conv3r<64, 0, 8><<<dim3(8, 1, 64), 256, 0, stream>>>(
      R64b, SP2, 1.f / 4096.f, wp3 + 6 * 9216, rb_b1, nullptr, nullptr, nullptr, R64c, SP3);
  conv3r<64, 1, 8><<<dim3(8, 1, 64), 256, 0, stream>>>(
      R64c, SP3, 1.f / 4096.f, wp3 + 8 * 9216, rb_b2, nullptr, R64b, nullptr, R64a, SP4);

  // rbs1: 64^2 -> 32^2 (skip src = R64a)
  conv3n<64, 2, 0, 4><<<dim3(8, 1, 64), 256, 0, stream>>>(
      R64a, SP4, 1.f / 4096.f, wp3 + 1 * 9216, rbs_b1 + 32, nullptr, nullptr, nullptr, R32a, SP5);
  conv3r<32, 2, 8><<<dim3(4, 1, 64), 256, 0, stream>>>(
      R32a, SP5, 1.f / 1024.f, wp3 + 4 * 9216, rbs_b2 + 32, rbs_bs + 32, R64a, wp1 + 1024, R32b, SP6);

  // rb1: 32^2 plain resblock (identity = R32b)
  conv3r<32, 0, 8><<<dim3(4, 1, 64), 256, 0, stream>>>(
      R32b, SP6, 1.f / 1024.f, wp3 + 7 * 9216, rb_b1 + 32, nullptr, nullptr, nullptr, R32c, SP7);
  conv3r<32, 1, 8><<<dim3(4, 1, 64), 256, 0, stream>>>(
      R32c, SP7, 1.f / 1024.f, wp3 + 9 * 9216, rb_b2 + 32, nullptr, R32b, nullptr, R32a, SP8);

  // rbs2: 32^2 -> 16^2 (skip src = R32a)
  conv3n<32, 2, 0, 8><<<dim3(2, 1, 64), 256, 0, stream>>>(
      R32a, SP8, 1.f / 1024.f, wp3 + 2 * 9216, rbs_b1 + 64, nullptr, nullptr, nullptr, R16a, SP9);
  conv3n<16, 1, 2, 8><<<dim3(2, 1, 64), 256, 0, stream>>>(
      R16a, SP9, 1.f / 256.f, wp3 + 5 * 9216, rbs_b2 + 64, rbs_bs + 64, R32a, wp1 + 2048, R16b, nullptr);

  // attention tail
  gates_kernel<<<80, 256, 0, stream>>>(text, attn_w, attn_b, G);
  scores_kernel<<<64, 256, 0, stream>>>(R16b, G, amapT);
  final_kernel<<<128, 256, 0, stream>>>(amapT, final_w, final_b, out);
}

// Round 10
// 300.898 us; speedup vs baseline: 1.5550x; 1.0360x over previous
//
#include <hip/hip_runtime.h>
#include <cstdint>
#include <cstddef>

#define INORM_EPS 1e-5f

typedef _Float16 f16;
typedef f16 f16x8 __attribute__((ext_vector_type(8)));
typedef f16 f16x4 __attribute__((ext_vector_type(4)));
typedef float f32x4 __attribute__((ext_vector_type(4)));

// ------- merged prep (zero SP, pack weights) + input stats partials -------
__global__ __launch_bounds__(256) void prep_stats(
    const float* __restrict__ rbs_w1, const float* __restrict__ rbs_w2,
    const float* __restrict__ rb_w1, const float* __restrict__ rb_w2,
    const float* __restrict__ rbs_ws, const float* __restrict__ conv1_w,
    const float* __restrict__ x, float2* __restrict__ SP,
    f16* __restrict__ wp3, f16* __restrict__ wp1, f16* __restrict__ wp7,
    float2* __restrict__ SPx8) {
  const int bx = blockIdx.x;
  if (bx >= 480) {
    const int g = bx - 480;
    const int map = g >> 3, chunk = g & 7;
    const float4* p = (const float4*)(x + (size_t)map * 65536 + (size_t)chunk * 8192);
    float s = 0.f, ss = 0.f;
    for (int i = threadIdx.x; i < 2048; i += 256) {
      float4 v = p[i];
      s += v.x + v.y + v.z + v.w;
      ss += v.x * v.x + v.y * v.y + v.z * v.z + v.w * v.w;
    }
    __shared__ float r0[256], r1[256];
    r0[threadIdx.x] = s;
    r1[threadIdx.x] = ss;
    __syncthreads();
    for (int off = 128; off > 0; off >>= 1) {
      if ((int)threadIdx.x < off) {
        r0[threadIdx.x] += r0[threadIdx.x + off];
        r1[threadIdx.x] += r1[threadIdx.x + off];
      }
      __syncthreads();
    }
    if (threadIdx.x == 0) SPx8[map * 8 + chunk] = make_float2(r0[0], r1[0]);
    return;
  }
  int i = bx * 256 + threadIdx.x;
  if (i < 20480) { SP[i] = make_float2(0.f, 0.f); return; }
  i -= 20480;
  if (i < 92160) {  // [mat][9 taps][2 halves][64 lanes][8] ; B-frag layout
    int mat = i / 9216, r = i % 9216;
    int p = r >> 10, f = (r >> 9) & 1, l = (r >> 3) & 63, j = r & 7;
    int co = f * 16 + (l & 15), ci = (l >> 4) * 8 + j;
    const float* src; int m;
    if (mat < 3) { src = rbs_w1; m = mat; }
    else if (mat < 6) { src = rbs_w2; m = mat - 3; }
    else if (mat < 8) { src = rb_w1; m = mat - 6; }
    else { src = rb_w2; m = mat - 8; }
    wp3[i] = (f16)src[m * 9216 + co * 288 + ci * 9 + p];
    return;
  }
  i -= 92160;
  if (i < 3072) {
    int mat = i / 1024, r = i % 1024;
    int f = r >> 9, l = (r >> 3) & 63, j = r & 7;
    wp1[i] = (f16)rbs_ws[mat * 1024 + (f * 16 + (l & 15)) * 32 + (l >> 4) * 8 + j];
    return;
  }
  i -= 3072;
  if (i >= 7168) return;
  int ky = i >> 10, f = (i >> 9) & 1, l = (i >> 3) & 63, j = i & 7;
  int k = (l >> 4) * 8 + j, kx = k >> 2, ci = k & 3;
  float v = 0.f;
  if (kx < 7 && ci < 3) v = conv1_w[(f * 16 + (l & 15)) * 147 + ci * 49 + ky * 7 + kx];
  wp7[i] = (f16)v;
}

// ---------------- MFMA 3x3 stride-1 conv, rolling row window --------------
// 3-deep row prefetch: rows i+2, i+3, i+4 in flight (9 outstanding loads).
template <int W, int SKIP, int RPB>
__global__ __launch_bounds__(256) void conv3r(
    const f16* __restrict__ Rin, const float2* __restrict__ SPin, float inv_hw,
    const f16* __restrict__ wp, const float* __restrict__ bias,
    const float* __restrict__ bias2, const f16* __restrict__ skip,
    const f16* __restrict__ wps, f16* __restrict__ Rout,
    float2* __restrict__ ostats) {
  constexpr int TPR = W / 16;
  constexpr int LEN = (RPB * TPR) / 4;
  const int t = threadIdx.x, w = t >> 6, l = t & 63;
  const int n = l & 15, q = l >> 4;
  const int b = blockIdx.z;
  const int tx = w % TPR;
  const int y0 = blockIdx.x * RPB + (w / TPR) * LEN;
  const int x = (tx << 4) + n;
  const f16* Rb = Rin + (size_t)b * W * W * 32;

  f16x8 sc, sh;
#pragma unroll
  for (int j = 0; j < 8; j++) {
    float2 s = SPin[b * 32 + q * 8 + j];
    float mean = s.x * inv_hw;
    float rstd = rsqrtf(s.y * inv_hw - mean * mean + INORM_EPS);
    sc[j] = (f16)rstd;
    sh[j] = (f16)(-mean * rstd);
  }

  f16x8 wf[18];
#pragma unroll
  for (int i = 0; i < 18; i++) wf[i] = *(const f16x8*)(wp + i * 512 + l * 8);
  f16x8 wsf0, wsf1;
  if (SKIP == 2) {
    wsf0 = *(const f16x8*)(wps + l * 8);
    wsf1 = *(const f16x8*)(wps + 512 + l * 8);
  }
  float b0 = bias[n], b1 = bias[16 + n];
  if (SKIP == 2) { b0 += bias2[n]; b1 += bias2[16 + n]; }

  f16* ro = Rout + (size_t)b * W * W * 32;
  const f16* sb = skip ? skip + (size_t)b * (SKIP == 2 ? 4 : 1) * W * W * 32 : nullptr;

  bool okc[3];
#pragma unroll
  for (int kx = 0; kx < 3; kx++) okc[kx] = (unsigned)(x + kx - 1) < (unsigned)W;

  auto rowload = [&](int gy, f16x8* dst) {
    int gyc = min(max(gy, 0), W - 1);
#pragma unroll
    for (int kx = 0; kx < 3; kx++) {
      int gxc = min(max(x + kx - 1, 0), W - 1);
      dst[kx] = *(const f16x8*)(Rb + ((size_t)gyc * W + gxc) * 32 + q * 8);
    }
  };
  auto rownorm = [&](int gy, const f16x8* src, f16x8* dst) {
    bool okr = (unsigned)gy < (unsigned)W;
#pragma unroll
    for (int kx = 0; kx < 3; kx++) {
      f16x8 v = src[kx] * sc + sh;
#pragma unroll
      for (int e = 0; e < 8; e++) v[e] = v[e] > (f16)0 ? v[e] : (f16)0;
      f16x8 z = {};
      dst[kx] = (okr && okc[kx]) ? v : z;
    }
  };

  float sm0 = 0.f, sq0 = 0.f, sm1 = 0.f, sq1 = 0.f;
  f16x8 win[9];
  f16x8 pf[3][3];
#pragma unroll
  for (int jj = 0; jj < 3; jj++) rowload(y0 + jj - 1, &win[jj * 3]);
  if (LEN > 1) rowload(y0 + 2, pf[0]);
  if (LEN > 2) rowload(y0 + 3, pf[1]);
#pragma unroll
  for (int jj = 0; jj < 3; jj++) rownorm(y0 + jj - 1, &win[jj * 3], &win[jj * 3]);

#pragma unroll
  for (int i = 0; i < LEN; i++) {
    int y = y0 + i;
    if (i + 3 < LEN) rowload(y0 + i + 4, pf[(i + 2) % 3]);
    f32x4 acc0 = {0.f, 0.f, 0.f, 0.f}, acc1 = {0.f, 0.f, 0.f, 0.f};
#pragma unroll
    for (int ky = 0; ky < 3; ky++) {
      int slot = (i + ky) % 3;
#pragma unroll
      for (int kx = 0; kx < 3; kx++) {
        f16x8 a = win[slot * 3 + kx];
        acc0 = __builtin_amdgcn_mfma_f32_16x16x32_f16(a, wf[2 * (ky * 3 + kx)], acc0, 0, 0, 0);
        acc1 = __builtin_amdgcn_mfma_f32_16x16x32_f16(a, wf[2 * (ky * 3 + kx) + 1], acc1, 0, 0, 0);
      }
    }
    if (SKIP == 2) {
      const int Ws = 2 * W;
      f16x8 as = *(const f16x8*)(sb + ((size_t)(2 * y) * Ws + 2 * x) * 32 + q * 8);
      acc0 = __builtin_amdgcn_mfma_f32_16x16x32_f16(as, wsf0, acc0, 0, 0, 0);
      acc1 = __builtin_amdgcn_mfma_f32_16x16x32_f16(as, wsf1, acc1, 0, 0, 0);
    }
#pragma unroll
    for (int r = 0; r < 4; r++) {
      size_t px = (size_t)y * W + (tx << 4) + q * 4 + r;
      float v0 = acc0[r] + b0;
      float v1 = acc1[r] + b1;
      if (SKIP == 1) {
        v0 += (float)sb[px * 32 + n];
        v1 += (float)sb[px * 32 + 16 + n];
      }
      ro[px * 32 + n] = (f16)v0;
      ro[px * 32 + 16 + n] = (f16)v1;
      sm0 += v0; sq0 += v0 * v0;
      sm1 += v1; sq1 += v1 * v1;
    }
    if (i + 1 < LEN) rownorm(y0 + i + 2, pf[i % 3], &win[(i % 3) * 3]);
  }
  if (ostats) {
    sm0 += __shfl_xor(sm0, 16); sm0 += __shfl_xor(sm0, 32);
    sq0 += __shfl_xor(sq0, 16); sq0 += __shfl_xor(sq0, 32);
    sm1 += __shfl_xor(sm1, 16); sm1 += __shfl_xor(sm1, 32);
    sq1 += __shfl_xor(sq1, 16); sq1 += __shfl_xor(sq1, 32);
    if (l < 16) {
      atomicAdd(&ostats[b * 32 + n].x, sm0);
      atomicAdd(&ostats[b * 32 + n].y, sq0);
      atomicAdd(&ostats[b * 32 + 16 + n].x, sm1);
      atomicAdd(&ostats[b * 32 + 16 + n].y, sq1);
    }
  }
}

// ---------------- MFMA 3x3 stride-2 conv, rolling row window --------------
// (Round-1-verified.) Window advances 2 rows per output row: loads 2 new
// rows instead of re-loading all 3 taps (1.5x -> ~1.06x input re-read),
// LEN=8-deep per-wave pipeline. Same MFMA order as conv3n => bit-identical.
template <int WIN>
__global__ __launch_bounds__(256) void conv3s2(
    const f16* __restrict__ Rin, const float2* __restrict__ SPin, float inv_hw,
    const f16* __restrict__ wp, const float* __restrict__ bias,
    f16* __restrict__ Rout, float2* __restrict__ ostats) {
  constexpr int WOUT = WIN / 2;
  constexpr int TPR = WOUT / 16;
  constexpr int RPB = 8;
  constexpr int LEN = (RPB * TPR) / 4;
  const int t = threadIdx.x, w = t >> 6, l = t & 63;
  const int n = l & 15, q = l >> 4;
  const int b = blockIdx.z;
  const int tx = w % TPR;
  const int y0 = blockIdx.x * RPB + (w / TPR) * LEN;
  const int x = (tx << 4) + n;  // output x
  const f16* Rb = Rin + (size_t)b * WIN * WIN * 32;

  f16x8 sc, sh;
#pragma unroll
  for (int j = 0; j < 8; j++) {
    float2 s = SPin[b * 32 + q * 8 + j];
    float mean = s.x * inv_hw;
    float rstd = rsqrtf(s.y * inv_hw - mean * mean + INORM_EPS);
    sc[j] = (f16)rstd;
    sh[j] = (f16)(-mean * rstd);
  }

  f16x8 wf[18];
#pragma unroll
  for (int i = 0; i < 18; i++) wf[i] = *(const f16x8*)(wp + i * 512 + l * 8);
  float b0 = bias[n], b1 = bias[16 + n];

  f16* ro = Rout + (size_t)b * WOUT * WOUT * 32;

  bool okc[3];
#pragma unroll
  for (int kx = 0; kx < 3; kx++) okc[kx] = (unsigned)(2 * x + kx - 1) < (unsigned)WIN;

  auto rowload = [&](int gy, f16x8* dst) {
    int gyc = min(max(gy, 0), WIN - 1);
#pragma unroll
    for (int kx = 0; kx < 3; kx++) {
      int gxc = min(max(2 * x + kx - 1, 0), WIN - 1);
      dst[kx] = *(const f16x8*)(Rb + ((size_t)gyc * WIN + gxc) * 32 + q * 8);
    }
  };
  auto rownorm = [&](int gy, const f16x8* src, f16x8* dst) {
    bool okr = (unsigned)gy < (unsigned)WIN;
#pragma unroll
    for (int kx = 0; kx < 3; kx++) {
      f16x8 v = src[kx] * sc + sh;
#pragma unroll
      for (int e = 0; e < 8; e++) v[e] = v[e] > (f16)0 ? v[e] : (f16)0;
      f16x8 z = {};
      dst[kx] = (okr && okc[kx]) ? v : z;
    }
  };

  float sm0 = 0.f, sq0 = 0.f, sm1 = 0.f, sq1 = 0.f;
  // win slot for window-relative row d (row = 2*y0-1+d) is d%3.
  f16x8 win[9], pa[3], pb[3];
#pragma unroll
  for (int jj = 0; jj < 3; jj++) {
    rowload(2 * y0 - 1 + jj, pa);
    rownorm(2 * y0 - 1 + jj, pa, &win[jj * 3]);
  }

#pragma unroll
  for (int i = 0; i < LEN; i++) {
    int y = y0 + i;
    if (i + 1 < LEN) {
      rowload(2 * y + 2, pa);
      rowload(2 * y + 3, pb);
    }
    f32x4 acc0 = {0.f, 0.f, 0.f, 0.f}, acc1 = {0.f, 0.f, 0.f, 0.f};
#pragma unroll
    for (int ky = 0; ky < 3; ky++) {
      int slot = (2 * i + ky) % 3;  // compile-time under unroll
#pragma unroll
      for (int kx = 0; kx < 3; kx++) {
        f16x8 a = win[slot * 3 + kx];
        acc0 = __builtin_amdgcn_mfma_f32_16x16x32_f16(a, wf[2 * (ky * 3 + kx)], acc0, 0, 0, 0);
        acc1 = __builtin_amdgcn_mfma_f32_16x16x32_f16(a, wf[2 * (ky * 3 + kx) + 1], acc1, 0, 0, 0);
      }
    }
#pragma unroll
    for (int r = 0; r < 4; r++) {
      size_t px = (size_t)y * WOUT + (tx << 4) + q * 4 + r;
      float v0 = acc0[r] + b0;
      float v1 = acc1[r] + b1;
      ro[px * 32 + n] = (f16)v0;
      ro[px * 32 + 16 + n] = (f16)v1;
      sm0 += v0; sq0 += v0 * v0;
      sm1 += v1; sq1 += v1 * v1;
    }
    if (i + 1 < LEN) {
      rownorm(2 * y + 2, pa, &win[((2 * i + 3) % 3) * 3]);
      rownorm(2 * y + 3, pb, &win[((2 * i + 4) % 3) * 3]);
    }
  }
  if (ostats) {
    sm0 += __shfl_xor(sm0, 16); sm0 += __shfl_xor(sm0, 32);
    sq0 += __shfl_xor(sq0, 16); sq0 += __shfl_xor(sq0, 32);
    sm1 += __shfl_xor(sm1, 16); sm1 += __shfl_xor(sm1, 32);
    sq1 += __shfl_xor(sq1, 16); sq1 += __shfl_xor(sq1, 32);
    if (l < 16) {
      atomicAdd(&ostats[b * 32 + n].x, sm0);
      atomicAdd(&ostats[b * 32 + n].y, sq0);
      atomicAdd(&ostats[b * 32 + 16 + n].x, sm1);
      atomicAdd(&ostats[b * 32 + 16 + n].y, sq1);
    }
  }
}

// ---------------- MFMA 3x3 conv (pipelined units): small stride-2 / 16x16 -
template <int WIN, int STRIDE, int SKIP, int RPB>
__global__ __launch_bounds__(256) void conv3n(
    const f16* __restrict__ Rin, const float2* __restrict__ SPin, float inv_hw,
    const f16* __restrict__ wp, const float* __restrict__ bias,
    const float* __restrict__ bias2, const f16* __restrict__ skip,
    const f16* __restrict__ wps, f16* __restrict__ Rout,
    float2* __restrict__ ostats) {
  constexpr int WOUT = WIN / STRIDE;
  constexpr int TPR = WOUT / 16;
  constexpr int UNITS = TPR * RPB;
  constexpr int U = UNITS / 4;
  static_assert(U >= 1, "need at least one unit per wave");
  constexpr int NB = (U >= 3) ? 3 : ((U >= 2) ? 2 : 1);
  const int t = threadIdx.x, w = t >> 6, l = t & 63;
  const int n = l & 15, q = l >> 4;
  const int b = blockIdx.z;
  const int yb = blockIdx.x * RPB;
  const f16* Rb = Rin + (size_t)b * WIN * WIN * 32;

  f16x8 sc, sh;
#pragma unroll
  for (int j = 0; j < 8; j++) {
    float2 s = SPin[b * 32 + q * 8 + j];
    float mean = s.x * inv_hw;
    float rstd = rsqrtf(s.y * inv_hw - mean * mean + INORM_EPS);
    sc[j] = (f16)rstd;
    sh[j] = (f16)(-mean * rstd);
  }

  f16x8 wf[18];
#pragma unroll
  for (int i = 0; i < 18; i++) wf[i] = *(const f16x8*)(wp + i * 512 + l * 8);
  f16x8 wsf0, wsf1;
  if (SKIP == 2) {
    wsf0 = *(const f16x8*)(wps + l * 8);
    wsf1 = *(const f16x8*)(wps + 512 + l * 8);
  }
  float b0 = bias[n], b1 = bias[16 + n];
  if (SKIP == 2) { b0 += bias2[n]; b1 += bias2[16 + n]; }

  f16* ro = Rout + (size_t)b * WOUT * WOUT * 32;
  const f16* sb = skip ? skip + (size_t)b * (SKIP == 2 ? 4 : 1) * WOUT * WOUT * 32 : nullptr;

  auto load_u = [&](int u, f16x8* a) {
    int ty = u / TPR, tx = u % TPR;
    int y = yb + ty;
#pragma unroll
    for (int kx = 0; kx < 3; kx++) {
      int gx = STRIDE * ((tx << 4) + n) + kx - 1;
      int gxc = min(max(gx, 0), WIN - 1);
#pragma unroll
      for (int ky = 0; ky < 3; ky++) {
        int gy = STRIDE * y + ky - 1;
        int gyc = min(max(gy, 0), WIN - 1);
        a[ky * 3 + kx] = *(const f16x8*)(Rb + ((size_t)gyc * WIN + gxc) * 32 + q * 8);
      }
    }
  };
  auto norm_u = [&](int u, f16x8* a) {
    int ty = u / TPR, tx = u % TPR;
    int y = yb + ty;
#pragma unroll
    for (int kx = 0; kx < 3; kx++) {
      int gx = STRIDE * ((tx << 4) + n) + kx - 1;
      bool okx = (unsigned)gx < (unsigned)WIN;
#pragma unroll
      for (int ky = 0; ky < 3; ky++) {
        int gy = STRIDE * y + ky - 1;
        bool ok = okx && ((unsigned)gy < (unsigned)WIN);
        f16x8 v = a[ky * 3 + kx] * sc + sh;
#pragma unroll
        for (int e = 0; e < 8; e++) v[e] = v[e] > (f16)0 ? v[e] : (f16)0;
        f16x8 z = {};
        a[ky * 3 + kx] = ok ? v : z;
      }
    }
  };

  float sm0 = 0.f, sq0 = 0.f, sm1 = 0.f, sq1 = 0.f;
  f16x8 buf[NB][9];
  load_u(w, buf[0]);
  if (U > 1) load_u(w + 4, buf[1 % NB]);
#pragma unroll
  for (int i = 0; i < U; i++) {
    int u = w + 4 * i;
    if (i + 2 < U) load_u(u + 8, buf[(i + 2) % NB]);
    f16x8* a = buf[i % NB];
    norm_u(u, a);
    int ty = u / TPR, tx = u % TPR;
    int y = yb + ty, x0 = tx << 4;
    f32x4 acc0 = {0.f, 0.f, 0.f, 0.f}, acc1 = {0.f, 0.f, 0.f, 0.f};
#pragma unroll
    for (int p = 0; p < 9; p++) {
      acc0 = __builtin_amdgcn_mfma_f32_16x16x32_f16(a[p], wf[2 * p], acc0, 0, 0, 0);
      acc1 = __builtin_amdgcn_mfma_f32_16x16x32_f16(a[p], wf[2 * p + 1], acc1, 0, 0, 0);
    }
    if (SKIP == 2) {
      const int Ws = 2 * WOUT;
      f16x8 as = *(const f16x8*)(sb + ((size_t)(2 * y) * Ws + 2 * (x0 + n)) * 32 + q * 8);
      acc0 = __builtin_amdgcn_mfma_f32_16x16x32_f16(as, wsf0, acc0, 0, 0, 0);
      acc1 = __builtin_amdgcn_mfma_f32_16x16x32_f16(as, wsf1, acc1, 0, 0, 0);
    }
#pragma unroll
    for (int r = 0; r < 4; r++) {
      size_t px = (size_t)y * WOUT + x0 + q * 4 + r;
      float v0 = acc0[r] + b0;
      float v1 = acc1[r] + b1;
      if (SKIP == 1) {
        v0 += (float)sb[px * 32 + n];
        v1 += (float)sb[px * 32 + 16 + n];
      }
      ro[px * 32 + n] = (f16)v0;
      ro[px * 32 + 16 + n] = (f16)v1;
      sm0 += v0; sq0 += v0 * v0;
      sm1 += v1; sq1 += v1 * v1;
    }
  }
  if (ostats) {
    sm0 += __shfl_xor(sm0, 16); sm0 += __shfl_xor(sm0, 32);
    sq0 += __shfl_xor(sq0, 16); sq0 += __shfl_xor(sq0, 32);
    sm1 += __shfl_xor(sm1, 16); sm1 += __shfl_xor(sm1, 32);
    sq1 += __shfl_xor(sq1, 16); sq1 += __shfl_xor(sq1, 32);
    if (l < 16) {
      atomicAdd(&ostats[b * 32 + n].x, sm0);
      atomicAdd(&ostats[b * 32 + n].y, sq0);
      atomicAdd(&ostats[b * 32 + 16 + n].x, sm1);
      atomicAdd(&ostats[b * 32 + 16 + n].y, sq1);
    }
  }
}

// ---------------- MFMA 7x7 s2 conv1: LDS-staged, 4-chunk pipelined --------
// Block: 8 output rows, 21-row LDS window (44,016 B). Serial stage = 7 rows
// (33%): A(0..6) -> {issue B || out0} -> write B -> {issue C || out1..3}
// -> write C -> {issue D || out4..6} -> write D -> out7.
__global__ __launch_bounds__(256) void conv7(
    const float* __restrict__ x, const float2* __restrict__ SPx8,
    const f16* __restrict__ wp, const float* __restrict__ bias,
    f16* __restrict__ Rout, float2* __restrict__ ostats) {
  __shared__ f16 lds[21 * 131 * 8];  // 44,016 B
  const int t = threadIdx.x, w = t >> 6, l = t & 63;
  const int n = l & 15, q = l >> 4;
  const int b = blockIdx.z;
  const int yb = blockIdx.x * 8;
  const float* Xb = x + (size_t)b * 3 * 65536;
  float mn[3], rs[3];
#pragma unroll
  for (int ci = 0; ci < 3; ci++) {
    float sx = 0.f, sxx = 0.f;
#pragma unroll
    for (int c = 0; c < 8; c++) {
      float2 v = SPx8[(b * 3 + ci) * 8 + c];
      sx += v.x; sxx += v.y;
    }
    mn[ci] = sx * (1.f / 65536.f);
    rs[ci] = rsqrtf(sxx * (1.f / 65536.f) - mn[ci] * mn[ci] + INORM_EPS);
  }
  f16x8 wf[14];
#pragma unroll
  for (int i = 0; i < 14; i++) wf[i] = *(const f16x8*)(wp + i * 512 + l * 8);
  float b0 = bias[n], b1 = bias[16 + n];

  // ---- stage A: rel rows 0..6 (input rows 2*yb-3+ri), coalesced ----
  for (int idx = t; idx < 7 * 262; idx += 256) {
    int ri = idx / 262, cl = idx - ri * 262;
    int row = 2 * yb - 3 + ri, col = cl - 3;
    bool ok = ((unsigned)row < 256u) && ((unsigned)col < 256u);
    f16x4 v = {};
    if (ok) {
      const float* p = Xb + (size_t)row * 256 + col;
      v[0] = (f16)((p[0] - mn[0]) * rs[0]);
      v[1] = (f16)((p[65536] - mn[1]) * rs[1]);
      v[2] = (f16)((p[131072] - mn[2]) * rs[2]);
    }
    *(f16x4*)(lds + ((ri * 131 + (cl >> 1)) * 8) + (cl & 1) * 4) = v;
  }
  __syncthreads();

  float sm0 = 0.f, sq0 = 0.f, sm1 = 0.f, sq1 = 0.f;
  f16* ro = Rout + (size_t)b * 16384 * 32;

  auto compute_chunk = [&](int i0, int i1) {
#pragma unroll
    for (int seg = 0; seg < 2; seg++) {
      const int tx = w + seg * 4;
      const int x0 = tx * 16;
      const int u = x0 + n + q;  // lds col-pair index for this lane
      for (int i = i0; i < i1; i++) {
        int y = yb + i;
        f32x4 acc0 = {0.f, 0.f, 0.f, 0.f}, acc1 = {0.f, 0.f, 0.f, 0.f};
#pragma unroll
        for (int ky = 0; ky < 7; ky++) {
          f16x8 a = *(const f16x8*)(lds + ((2 * i + ky) * 131 + u) * 8);
          acc0 = __builtin_amdgcn_mfma_f32_16x16x32_f16(a, wf[2 * ky], acc0, 0, 0, 0);
          acc1 = __builtin_amdgcn_mfma_f32_16x16x32_f16(a, wf[2 * ky + 1], acc1, 0, 0, 0);
        }
#pragma unroll
        for (int r = 0; r < 4; r++) {
          size_t px = (size_t)y * 128 + x0 + q * 4 + r;
          float v0 = acc0[r] + b0;
          float v1 = acc1[r] + b1;
          ro[px * 32 + n] = (f16)v0;
          ro[px * 32 + 16 + n] = (f16)v1;
          sm0 += v0; sq0 += v0 * v0;
          sm1 += v1; sq1 += v1 * v1;
        }
      }
    }
  };

  // ---- issue chunk-B loads (rel rows 7..12; input rows 2*yb+4+ri) ----
  float ub0[7], ub1[7], ub2[7];
#pragma unroll
  for (int it = 0; it < 7; it++) {
    int idx = t + it * 256;
    int ri = idx / 262, cl = idx - ri * 262;
    int row = 2 * yb + 4 + ri, col = cl - 3;
    bool ok = (idx < 1572) && (row < 256) && ((unsigned)col < 256u);
    const float* p = Xb + (size_t)(ok ? row : 0) * 256 + (ok ? col : 0);
    ub0[it] = p[0];
    ub1[it] = p[65536];
    ub2[it] = p[131072];
  }

  // out row 0 (rel rows 0..6) — B loads in flight
  compute_chunk(0, 1);

  // ---- convert + write chunk B (rel rows 7..12) ----
#pragma unroll
  for (int it = 0; it < 7; it++) {
    int idx = t + it * 256;
    if (idx < 1572) {
      int ri = idx / 262, cl = idx - ri * 262;
      int row = 2 * yb + 4 + ri, col = cl - 3;
      bool ok = (row < 256) && ((unsigned)col < 256u);
      f16x4 v = {};
      if (ok) {
        v[0] = (f16)((ub0[it] - mn[0]) * rs[0]);
        v[1] = (f16)((ub1[it] - mn[1]) * rs[1]);
        v[2] = (f16)((ub2[it] - mn[2]) * rs[2]);
      }
      *(f16x4*)(lds + (((7 + ri) * 131 + (cl >> 1)) * 8) + (cl & 1) * 4) = v;
    }
  }

  // ---- issue chunk-C loads (rel rows 13..18; input rows 2*yb+10+ri) ----
  float uc0[7], uc1[7], uc2[7];
#pragma unroll
  for (int it = 0; it < 7; it++) {
    int idx = t + it * 256;
    int ri = idx / 262, cl = idx - ri * 262;
    int row = 2 * yb + 10 + ri, col = cl - 3;
    bool ok = (idx < 1572) && (row < 256) && ((unsigned)col < 256u);
    const float* p = Xb + (size_t)(ok ? row : 0) * 256 + (ok ? col : 0);
    uc0[it] = p[0];
    uc1[it] = p[65536];
    uc2[it] = p[131072];
  }
  __syncthreads();

  // out rows 1..3 (rel rows <=12) — C loads in flight
  compute_chunk(1, 4);

  // ---- convert + write chunk C (rel rows 13..18) ----
#pragma unroll
  for (int it = 0; it < 7; it++) {
    int idx = t + it * 256;
    if (idx < 1572) {
      int ri = idx / 262, cl = idx - ri * 262;
      int row = 2 * yb + 10 + ri, col = cl - 3;
      bool ok = (row < 256) && ((unsigned)col < 256u);
      f16x4 v = {};
      if (ok) {
        v[0] = (f16)((uc0[it] - mn[0]) * rs[0]);
        v[1] = (f16)((uc1[it] - mn[1]) * rs[1]);
        v[2] = (f16)((uc2[it] - mn[2]) * rs[2]);
      }
      *(f16x4*)(lds + (((13 + ri) * 131 + (cl >> 1)) * 8) + (cl & 1) * 4) = v;
    }
  }

  // ---- issue chunk-D loads (rel rows 19..20; input rows 2*yb+16+ri) ----
  float ud0[3], ud1[3], ud2[3];
#pragma unroll
  for (int it = 0; it < 3; it++) {
    int idx = t + it * 256;
    int ri = idx / 262, cl = idx - ri * 262;
    int row = 2 * yb + 16 + ri, col = cl - 3;
    bool ok = (idx < 524) && (row < 256) && ((unsigned)col < 256u);
    const float* p = Xb + (size_t)(ok ? row : 0) * 256 + (ok ? col : 0);
    ud0[it] = p[0];
    ud1[it] = p[65536];
    ud2[it] = p[131072];
  }
  __syncthreads();

  // out rows 4..6 (rel rows <=18) — D loads in flight
  compute_chunk(4, 7);

  // ---- convert + write chunk D (rel rows 19..20) ----
#pragma unroll
  for (int it = 0; it < 3; it++) {
    int idx = t + it * 256;
    if (idx < 524) {
      int ri = idx / 262, cl = idx - ri * 262;
      int row = 2 * yb + 16 + ri, col = cl - 3;
      bool ok = (row < 256) && ((unsigned)col < 256u);
      f16x4 v = {};
      if (ok) {
        v[0] = (f16)((ud0[it] - mn[0]) * rs[0]);
        v[1] = (f16)((ud1[it] - mn[1]) * rs[1]);
        v[2] = (f16)((ud2[it] - mn[2]) * rs[2]);
      }
      *(f16x4*)(lds + (((19 + ri) * 131 + (cl >> 1)) * 8) + (cl & 1) * 4) = v;
    }
  }
  __syncthreads();

  // out row 7 (rel rows 14..20)
  compute_chunk(7, 8);

  sm0 += __shfl_xor(sm0, 16); sm0 += __shfl_xor(sm0, 32);
  sq0 += __shfl_xor(sq0, 16); sq0 += __shfl_xor(sq0, 32);
  sm1 += __shfl_xor(sm1, 16); sm1 += __shfl_xor(sm1, 32);
  sq1 += __shfl_xor(sq1, 16); sq1 += __shfl_xor(sq1, 32);
  if (l < 16) {
    atomicAdd(&ostats[b * 32 + n].x, sm0);
    atomicAdd(&ostats[b * 32 + n].y, sq0);
    atomicAdd(&ostats[b * 32 + 16 + n].x, sm1);
    atomicAdd(&ostats[b * 32 + 16 + n].y, sq1);
  }
}

// ---------------- tail stage 1: gates G[o][b] -----------------------------
__global__ __launch_bounds__(256) void gates_kernel(
    const float* __restrict__ text, const float* __restrict__ attn_w,
    const float* __restrict__ attn_b, float* __restrict__ G) {
  __shared__ float s_text[64 * 257];
  __shared__ float s_w[16 * 256];
  const int t = threadIdx.x, wv = t >> 6, lane = t & 63;
  const int o0 = blockIdx.x * 16;
  for (int d = t; d < 16384; d += 256) {
    int b = d >> 8, k = d & 255;
    s_text[b * 257 + k] = text[d];
  }
  for (int d = t; d < 4096; d += 256) s_w[d] = attn_w[(size_t)o0 * 256 + d];
  __syncthreads();
  float acc[4];
#pragma unroll
  for (int j = 0; j < 4; j++) acc[j] = attn_b[o0 + wv * 4 + j];
  for (int k = 0; k < 256; k++) {
    float tv = s_text[lane * 257 + k];
#pragma unroll
    for (int j = 0; j < 4; j++) acc[j] = fmaf(s_w[(wv * 4 + j) * 256 + k], tv, acc[j]);
  }
#pragma unroll
  for (int j = 0; j < 4; j++) {
    int o = o0 + wv * 4 + j;
    G[o * 64 + lane] = 1.f / (1.f + __expf(-acc[j]));
  }
}

// ---------------- tail stage 2: scores -> softmax -> amapT ----------------
__global__ __launch_bounds__(256) void scores_kernel(
    const f16* __restrict__ feat, const float* __restrict__ G,
    float* __restrict__ amapT) {
  __shared__ float s_feat[256 * 33];
  __shared__ float s_gate[1280];
  __shared__ float s_scores[5 * 32];
  __shared__ float s_probs[5 * 32];
  const int b = blockIdx.x;
  const int t = threadIdx.x;

  for (int i = t; i < 8192; i += 256)
    s_feat[(i >> 5) * 33 + (i & 31)] = (float)feat[(size_t)b * 8192 + i];
  for (int i = t; i < 1280; i += 256) s_gate[i] = G[i * 64 + b];
  __syncthreads();

  if (t < 160) {
    int h = t >> 5, c = t & 31;
    float acc = 0.f;
    for (int ij = 0; ij < 256; ij++) acc += s_gate[h * 256 + ij] * s_feat[ij * 33 + c];
    s_scores[t] = acc;
  }
  __syncthreads();

  if (t < 5) {
    float mx = -1e30f;
    for (int c = 0; c < 32; c++) mx = fmaxf(mx, s_scores[t * 32 + c]);
    float sum = 0.f;
    for (int c = 0; c < 32; c++) {
      float e = __expf(s_scores[t * 32 + c] - mx);
      s_probs[t * 32 + c] = e;
      sum += e;
    }
    float inv = 1.f / sum;
    for (int c = 0; c < 32; c++) s_probs[t * 32 + c] *= inv;
  }
  __syncthreads();

  for (int h = 0; h < 5; h++) {
    float acc = 0.f;
    for (int c = 0; c < 32; c++) acc += s_probs[h * 32 + c] * s_feat[t * 33 + c];
    amapT[(h * 256 + t) * 64 + b] = acc;
  }
}

// ---------------- tail stage 3: final linear, k split across waves --------
__global__ __launch_bounds__(256) void final_kernel(
    const float* __restrict__ amapT, const float* __restrict__ final_w,
    const float* __restrict__ final_b, float* __restrict__ out) {
  __shared__ float s_w[4 * 1280];
  __shared__ float s_red[4][4][64];
  const int t = threadIdx.x, wv = t >> 6, lane = t & 63;
  const int e0 = blockIdx.x * 4;
  for (int d = t; d < 5120; d += 256) s_w[d] = final_w[(size_t)e0 * 1280 + d];
  __syncthreads();
  const int k0 = wv * 320;
  float acc[4] = {0.f, 0.f, 0.f, 0.f};
  for (int k = k0; k < k0 + 320; k++) {
    float av = amapT[k * 64 + lane];
#pragma unroll
    for (int e = 0; e < 4; e++) acc[e] = fmaf(s_w[e * 1280 + k], av, acc[e]);
  }
#pragma unroll
  for (int e = 0; e < 4; e++) s_red[wv][e][lane] = acc[e];
  __syncthreads();
  if (wv == 0) {
#pragma unroll
    for (int e = 0; e < 4; e++) {
      float v = s_red[0][e][lane] + s_red[1][e][lane] + s_red[2][e][lane] +
                s_red[3][e][lane] + final_b[e0 + e];
      out[(size_t)lane * 512 + e0 + e] = v;
    }
  }
}

// -------------------------------------------------------------------------
extern "C" void kernel_launch(void* const* d_in, const int* in_sizes, int n_in,
                              void* d_out, int out_size, void* d_ws, size_t ws_size,
                              hipStream_t stream) {
  (void)in_sizes; (void)n_in; (void)out_size; (void)ws_size;
  const float* x       = (const float*)d_in[0];
  const float* text    = (const float*)d_in[1];
  const float* conv1_w = (const float*)d_in[2];
  const float* conv1_b = (const float*)d_in[3];
  const float* rbs_w1  = (const float*)d_in[4];
  const float* rbs_b1  = (const float*)d_in[5];
  const float* rbs_w2  = (const float*)d_in[6];
  const float* rbs_b2  = (const float*)d_in[7];
  const float* rbs_ws  = (const float*)d_in[8];
  const float* rbs_bs  = (const float*)d_in[9];
  const float* rb_w1   = (const float*)d_in[10];
  const float* rb_b1   = (const float*)d_in[11];
  const float* rb_w2   = (const float*)d_in[12];
  const float* rb_b2   = (const float*)d_in[13];
  const float* attn_w  = (const float*)d_in[14];
  const float* attn_b  = (const float*)d_in[15];
  const float* final_w = (const float*)d_in[16];
  const float* final_b = (const float*)d_in[17];
  float* out = (float*)d_out;

  char* wsb = (char*)d_ws;
  float2* SPx8 = (float2*)(wsb + 0);          // 1536 float2 (stats partials)
  f16*   R128 = (f16*)(wsb + 35145728);       // 67,108,864
  f16*   R64a = (f16*)(wsb + 102254592);      // 16,777,216
  f16*   R64b = (f16*)(wsb + 119031808);
  f16*   R64c = (f16*)(wsb + 135809024);
  f16*   R32a = (f16*)(wsb + 152586240);      // 4,194,304
  f16*   R32b = (f16*)(wsb + 156780544);
  f16*   R32c = (f16*)(wsb + 160974848);
  f16*   R16a = (f16*)(wsb + 165169152);      // 1,048,576
  f16*   R16b = (f16*)(wsb + 166217728);
  float2* SP  = (float2*)(wsb + 167266304);   // 10*2048 float2
  f16*   wp3  = (f16*)(wsb + 167431680);      // 10*9216
  f16*   wp1  = (f16*)(wsb + 167616000);      // 3*1024
  f16*   wp7  = (f16*)(wsb + 167622144);      // 7168
  float* G     = (float*)(wsb + 167636480);   // 1280*64
  float* amapT = (float*)(wsb + 167964160);   // 1280*64
  float2* SP0 = SP + 0 * 2048;
  float2* SP1 = SP + 1 * 2048;
  float2* SP2 = SP + 2 * 2048;
  float2* SP3 = SP + 3 * 2048;
  float2* SP4 = SP + 4 * 2048;
  float2* SP5 = SP + 5 * 2048;
  float2* SP6 = SP + 6 * 2048;
  float2* SP7 = SP + 7 * 2048;
  float2* SP8 = SP + 8 * 2048;
  float2* SP9 = SP + 9 * 2048;

  // merged prep (zero SP, pack weights) + input stats partials
  prep_stats<<<2016, 256, 0, stream>>>(rbs_w1, rbs_w2, rb_w1, rb_w2, rbs_ws,
                                       conv1_w, x, SP, wp3, wp1, wp7, SPx8);

  // conv1: 7x7 s2, 3->32, 256^2 -> 128^2 (LDS-staged, 4-chunk pipelined)
  conv7<<<dim3(16, 1, 64), 256, 0, stream>>>(x, SPx8, wp7, conv1_b, R128, SP0);

  // rbs0: 128^2 -> 64^2 (rolling-window stride-2)
  conv3s2<128><<<dim3(8, 1, 64), 256, 0, stream>>>(
      R128, SP0, 1.f / 16384.f, wp3, rbs_b1, R64a, SP1);
  conv3r<64, 2, 8><<<dim3(8, 1, 64), 256, 0, stream>>>(
      R64a, SP1, 1.f / 4096.f, wp3 + 3 * 9216, rbs_b2, rbs_bs, R128, wp1, R64b, SP2);

  // rb0: 64^2 plain resblock (identity = R64b)
  conv3r<64, 0, 8><<<dim3(8, 1, 64), 256, 0, stream>>>(
      R64b, SP2, 1.f / 4096.f, wp3 + 6 * 9216, rb_b1, nullptr, nullptr, nullptr, R64c, SP3);
  conv3r<64, 1, 8><<<dim3(8, 1, 64), 256, 0, stream>>>(
      R64c, SP3, 1.f / 4096.f, wp3 + 8 * 9216, rb_b2, nullptr, R64b, nullptr, R64a, SP4);

  // rbs1: 64^2 -> 32^2 (rolling-window stride-2; skip src = R64a)
  conv3s2<64><<<dim3(4, 1, 64), 256, 0, stream>>>(
      R64a, SP4, 1.f / 4096.f, wp3 + 1 * 9216, rbs_b1 + 32, R32a, SP5);
  conv3r<32, 2, 8><<<dim3(4, 1, 64), 256, 0, stream>>>(
      R32a, SP5, 1.f / 1024.f, wp3 + 4 * 9216, rbs_b2 + 32, rbs_bs + 32, R64a, wp1 + 1024, R32b, SP6);

  // rb1: 32^2 plain resblock (identity = R32b)
  conv3r<32, 0, 8><<<dim3(4, 1, 64), 256, 0, stream>>>(
      R32b, SP6, 1.f / 1024.f, wp3 + 7 * 9216, rb_b1 + 32, nullptr, nullptr, nullptr, R32c, SP7);
  conv3r<32, 1, 8><<<dim3(4, 1, 64), 256, 0, stream>>>(
      R32c, SP7, 1.f / 1024.f, wp3 + 9 * 9216, rb_b2 + 32, nullptr, R32b, nullptr, R32a, SP8);

  // rbs2: 32^2 -> 16^2 (skip src = R32a)
  conv3n<32, 2, 0, 8><<<dim3(2, 1, 64), 256, 0, stream>>>(
      R32a, SP8, 1.f / 1024.f, wp3 + 2 * 9216, rbs_b1 + 64, nullptr, nullptr, nullptr, R16a, SP9);
  conv3n<16, 1, 2, 8><<<dim3(2, 1, 64), 256, 0, stream>>>(
      R16a, SP9, 1.f / 256.f, wp3 + 5 * 9216, rbs_b2 + 64, rbs_bs + 64, R32a, wp1 + 2048, R16b, nullptr);

  // attention tail
  gates_kernel<<<80, 256, 0, stream>>>(text, attn_w, attn_b, G);
  scores_kernel<<<64, 256, 0, stream>>>(R16b, G, amapT);
  final_kernel<<<128, 256, 0, stream>>>(amapT, final_w, final_b, out);
}